// Round 19
// baseline (188.551 us; speedup 1.0000x reference)
//
#include <hip/hip_runtime.h>

typedef unsigned short ushort_t;
typedef __bf16 bf16x8 __attribute__((ext_vector_type(8)));
typedef float f32x4 __attribute__((ext_vector_type(4)));

#define T_DIM 2048
#define C_DIM 1024
#define H_NUM 16
#define D_DIM 64

__device__ __forceinline__ ushort_t f2bf(float f){
  unsigned v = __float_as_uint(f);
  return (ushort_t)((v + 0x7fffu + ((v >> 16) & 1u)) >> 16);
}
__device__ __forceinline__ float bf2f(ushort_t u){
  return __uint_as_float(((unsigned)u) << 16);
}

typedef __attribute__((address_space(1))) const unsigned int* gas1_t;
typedef __attribute__((address_space(3))) unsigned int* las3_t;

__device__ __forceinline__ void gload_lds16(const void* g, void* l){
  __builtin_amdgcn_global_load_lds((gas1_t)g, (las3_t)l, 16, 0, 0);
}

// ---------------- prep: convert x (blocks >=1024) + transpose 4 weights ----------------
__global__ __launch_bounds__(256) void prep_kernel(
    const float* __restrict__ x, ushort_t* __restrict__ xb,
    const float* __restrict__ w0, const float* __restrict__ w1,
    const float* __restrict__ w2, const float* __restrict__ w3,
    ushort_t* __restrict__ t0, ushort_t* __restrict__ t1,
    ushort_t* __restrict__ t2, ushort_t* __restrict__ t3)
{
  __shared__ float tl[64][65];
  const int bid = blockIdx.x;
  const int tid = threadIdx.x;
  if (bid >= 1024){
    int i = ((bid - 1024) * 256 + tid) * 4;
    float4 v = *reinterpret_cast<const float4*>(x + i);
    ushort4 o;
    o.x = f2bf(v.x); o.y = f2bf(v.y); o.z = f2bf(v.z); o.w = f2bf(v.w);
    *reinterpret_cast<ushort4*>(xb + i) = o;
    return;
  }
  const int which = bid >> 8;
  const float* W = which==0 ? w0 : which==1 ? w1 : which==2 ? w2 : w3;
  ushort_t* WT   = which==0 ? t0 : which==1 ? t1 : which==2 ? t2 : t3;
  const int tile = bid & 255;
  const int k0 = (tile & 15) * 64;
  const int n0 = (tile >> 4) * 64;
#pragma unroll
  for (int i = 0; i < 16; ++i){
    int idx = tid + i * 256;
    int r = idx >> 6, c = idx & 63;
    tl[r][c] = W[(k0 + r) * C_DIM + n0 + c];
  }
  __syncthreads();
#pragma unroll
  for (int i = 0; i < 16; ++i){
    int idx = tid + i * 256;
    int r = idx >> 6, c = idx & 63;
    WT[(n0 + r) * C_DIM + k0 + c] = f2bf(tl[c][r]);
  }
}

// ---------------- GEMM: BM=64 x BN=128 ----------------
template<int MODE>
__global__ __launch_bounds__(256) void gemm_kernel(
    const ushort_t* __restrict__ A,
    const ushort_t* __restrict__ bt0, const ushort_t* __restrict__ bt1, const ushort_t* __restrict__ bt2,
    const float* __restrict__ bias0, const float* __restrict__ bias1, const float* __restrict__ bias2,
    ushort_t* __restrict__ o0, ushort_t* __restrict__ o1, ushort_t* __restrict__ o2,
    float* __restrict__ fo)
{
  __shared__ __align__(16) ushort_t Alds[64 * 32];
  __shared__ __align__(16) ushort_t Blds[128 * 32];
  const int tid = threadIdx.x;
  const int l15 = tid & 15, g = (tid & 63) >> 4;
  const int w = tid >> 6, wr = w >> 1, wc = w & 1;
  const int m0 = blockIdx.x * 64;
  int byy = blockIdx.y;
  int sel = 0;
  const ushort_t* BT; const float* bias; ushort_t* outp;
  if (MODE == 0){
    sel = byy >> 3; byy &= 7;
    BT   = sel==0 ? bt0 : (sel==1 ? bt1 : bt2);
    bias = sel==0 ? bias0 : (sel==1 ? bias1 : bias2);
    outp = sel==0 ? o0 : (sel==1 ? o1 : o2);
  } else { BT = bt0; bias = bias0; outp = o0; }
  const int n0 = byy * 128;

  const int c0 = tid, c1 = tid + 256;
  const ushort_t* Asrc  = A + (m0 + (c0 >> 2)) * C_DIM + (c0 & 3) * 8;
  const ushort_t* Bsrc0 = BT + (n0 + (c0 >> 2)) * C_DIM + (c0 & 3) * 8;
  const ushort_t* Bsrc1 = BT + (n0 + (c1 >> 2)) * C_DIM + (c1 & 3) * 8;

  f32x4 acc[2][4] = {};

  for (int kt = 0; kt < 32; ++kt){
    const int ko = kt * 32;
    gload_lds16(Asrc + ko, &Alds[c0 * 8]);
    gload_lds16(Bsrc0 + ko, &Blds[c0 * 8]);
    gload_lds16(Bsrc1 + ko, &Blds[c1 * 8]);
    __syncthreads();
    bf16x8 af[2], bfr[4];
#pragma unroll
    for (int i = 0; i < 2; ++i)
      af[i] = *reinterpret_cast<const bf16x8*>(&Alds[(wr * 32 + i * 16 + l15) * 32 + g * 8]);
#pragma unroll
    for (int j = 0; j < 4; ++j)
      bfr[j] = *reinterpret_cast<const bf16x8*>(&Blds[(wc * 64 + j * 16 + l15) * 32 + g * 8]);
#pragma unroll
    for (int i = 0; i < 2; ++i)
#pragma unroll
      for (int j = 0; j < 4; ++j)
        acc[i][j] = __builtin_amdgcn_mfma_f32_16x16x32_bf16(af[i], bfr[j], acc[i][j], 0, 0, 0);
    __syncthreads();
  }

  float bvv[4];
#pragma unroll
  for (int j = 0; j < 4; ++j) bvv[j] = bias[n0 + wc * 64 + j * 16 + l15];

  if (MODE == 1){
#pragma unroll
    for (int i = 0; i < 2; ++i)
#pragma unroll
      for (int j = 0; j < 4; ++j)
#pragma unroll
        for (int e = 0; e < 4; ++e){
          int t = m0 + wr * 32 + i * 16 + g * 4 + e;
          int c = n0 + wc * 64 + j * 16 + l15;
          fo[t * C_DIM + c] = acc[i][j][e] + bvv[j];
        }
    return;
  }

  if (sel == 2){
#pragma unroll
    for (int i = 0; i < 2; ++i){
#pragma unroll
      for (int j = 0; j < 4; ++j){
        int c = n0 + wc * 64 + j * 16 + l15;
        int hh = c >> 6, d = c & 63;
        int t0e = m0 + wr * 32 + i * 16 + g * 4;
        ushort4 o;
        o.x = f2bf(acc[i][j][0] + bvv[j]);
        o.y = f2bf(acc[i][j][1] + bvv[j]);
        o.z = f2bf(acc[i][j][2] + bvv[j]);
        o.w = f2bf(acc[i][j][3] + bvv[j]);
        *reinterpret_cast<ushort4*>(outp + (size_t)(hh * D_DIM + d) * T_DIM + t0e) = o;
      }
    }
  } else {
#pragma unroll
    for (int i = 0; i < 2; ++i){
#pragma unroll
      for (int j = 0; j < 4; ++j){
#pragma unroll
        for (int e = 0; e < 4; ++e){
          int t = m0 + wr * 32 + i * 16 + g * 4 + e;
          int c = n0 + wc * 64 + j * 16 + l15;
          int hh = c >> 6, d = c & 63;
          outp[((size_t)(hh * T_DIM) + t) * D_DIM + d] = f2bf(acc[i][j][e] + bvv[j]);
        }
      }
    }
  }
}

// ---------------- RoPE ----------------
__global__ void rope_kernel(ushort_t* __restrict__ Qb, ushort_t* __restrict__ Kb){
  int gid = blockIdx.x * 256 + threadIdx.x;
  int which = gid >> 20;
  int r = gid & ((1 << 20) - 1);
  int i = r & 31;
  int t = (r >> 5) & 2047;
  int hh = r >> 16;
  ushort_t* P = which ? Kb : Qb;
  unsigned* p = reinterpret_cast<unsigned*>(P + ((hh * T_DIM) + t) * D_DIM + 2 * i);
  unsigned pv = *p;
  float x0 = bf2f((ushort_t)(pv & 0xffffu));
  float x1 = bf2f((ushort_t)(pv >> 16));
  float ang = (float)t * __expf((float)i * -0.2878231366242558f);
  float sn, cs;
  __sincosf(ang, &sn, &cs);
  float y0 = x0 * cs - x1 * sn;
  float y1 = x1 * cs + x0 * sn;
  *p = (unsigned)f2bf(y0) | (((unsigned)f2bf(y1)) << 16);
}

// ---------------- attention: snake + sum-only pass 1 + BARRIER-FREE pass 2 ----------------
// Grid 512 x 256 thr; xcd=lin&7 -> heads {2x,2x+1}; SNAKE qi (per-CU pair sums to 33 tiles).
// Pass 2: wave w owns q-rows [w*16, w*16+16) x ALL 64 cols per tile -> P lives in a
// wave-PRIVATE LDS stripe; PV reads only own stripe => NO barriers in the k-loop.
// Waves run as independent streams; compiler pipelines loads across tiles freely.
__global__ __launch_bounds__(256) void attn_kernel(
    const ushort_t* __restrict__ Qb, const ushort_t* __restrict__ Kb,
    const ushort_t* __restrict__ Vt, float* __restrict__ att, ushort_t* __restrict__ ya)
{
  __shared__ __align__(16) ushort_t Plds[64 * 72];   // 4 wave-private stripes of 16 rows
  __shared__ float l_sh[64];

  const int tid = threadIdx.x;
  const int l15 = tid & 15, g = (tid & 63) >> 4;
  const int w = tid >> 6;
  const int lin = (int)blockIdx.x;
  const int h = 2 * (lin & 7) + ((lin >> 3) & 1);
  const int r_ = lin >> 4;
  const int qi = (r_ < 16) ? (31 - r_) : (r_ - 16);   // snake
  const int q0 = qi * 64;
  const int nkt = qi + 1;

  const ushort_t* Qh = Qb + h * T_DIM * D_DIM;
  const ushort_t* Kh = Kb + h * T_DIM * D_DIM;
  const ushort_t* Vh = Vt + h * D_DIM * T_DIM;
  float* atth = att + (size_t)h * T_DIM * T_DIM;

  const f32x4 fz = {0.f, 0.f, 0.f, 0.f};
  const float scale = 0.125f;

  // ---- pass 1 (swapped operands, sum-only): wave w owns queries q0+w*16+l15 ----
  {
    const int qloc = w * 16 + l15;
    const int qglob = q0 + qloc;
    bf16x8 qT[2];
#pragma unroll
    for (int ks = 0; ks < 2; ++ks)
      qT[ks] = *reinterpret_cast<const bf16x8*>(Qh + qglob * D_DIM + ks * 32 + g * 8);

    float la[4] = {0.f, 0.f, 0.f, 0.f};

    for (int kt = 0; kt < nkt; ++kt){
      f32x4 sc[4];
      sc[0] = fz; sc[1] = fz; sc[2] = fz; sc[3] = fz;
#pragma unroll
      for (int mblk = 0; mblk < 4; ++mblk){
#pragma unroll
        for (int ks = 0; ks < 2; ++ks){
          bf16x8 kfT = *reinterpret_cast<const bf16x8*>(
              Kh + (kt * 64 + mblk * 16 + l15) * D_DIM + ks * 32 + g * 8);
          sc[mblk] = __builtin_amdgcn_mfma_f32_16x16x32_bf16(kfT, qT[ks], sc[mblk], 0, 0, 0);
        }
      }
      if (kt == qi){
        const int kbase = kt * 64 + g * 4;
#pragma unroll
        for (int mblk = 0; mblk < 4; ++mblk)
#pragma unroll
          for (int j = 0; j < 4; ++j){
            float s = sc[mblk][j] * scale;
            if ((kbase + mblk * 16 + j) > qglob) s = -1e30f;
            la[mblk] += __expf(s);
          }
      } else {
#pragma unroll
        for (int mblk = 0; mblk < 4; ++mblk)
#pragma unroll
          for (int j = 0; j < 4; ++j)
            la[mblk] += __expf(sc[mblk][j] * scale);
      }
    }

    float s = (la[0] + la[1]) + (la[2] + la[3]);
    s += __shfl_xor(s, 16);
    s += __shfl_xor(s, 32);
    if (g == 0) l_sh[qloc] = s;
  }
  __syncthreads();   // the ONLY block-wide barrier

  // ---- pass 2: wave-private stripes, no barriers ----
  ushort_t* Pb = &Plds[(w * 16) * 72];        // this wave's 16-row stripe
  float Li[4];
#pragma unroll
  for (int j = 0; j < 4; ++j)
    Li[j] = 1.0f / l_sh[w * 16 + g * 4 + j];

  bf16x8 qf[2];
#pragma unroll
  for (int ks = 0; ks < 2; ++ks)
    qf[ks] = *reinterpret_cast<const bf16x8*>(
        Qh + (q0 + w * 16 + l15) * D_DIM + ks * 32 + g * 8);

  f32x4 yac[4];
  yac[0] = fz; yac[1] = fz; yac[2] = fz; yac[3] = fz;

  for (int kt = 0; kt < nkt; ++kt){
    // QK^T: 16 rows x 64 keys (4 n-blocks)
    f32x4 sac[4];
    sac[0] = fz; sac[1] = fz; sac[2] = fz; sac[3] = fz;
#pragma unroll
    for (int ns = 0; ns < 4; ++ns){
#pragma unroll
      for (int ks = 0; ks < 2; ++ks){
        bf16x8 kf = *reinterpret_cast<const bf16x8*>(
            Kh + (kt * 64 + ns * 16 + l15) * D_DIM + ks * 32 + g * 8);
        sac[ns] = __builtin_amdgcn_mfma_f32_16x16x32_bf16(qf[ks], kf, sac[ns], 0, 0, 0);
      }
    }

    const bool diag = (kt == qi);
#pragma unroll
    for (int ns = 0; ns < 4; ++ns)
#pragma unroll
      for (int j = 0; j < 4; ++j){
        float s = sac[ns][j] * scale;
        int qq = g * 4 + j;                  // stripe-local row [0,16)
        int cc = ns * 16 + l15;              // key [0,64)
        if (diag && cc > (w * 16 + qq)) s = -1e30f;
        float p = __expf(s) * Li[j];
        Pb[qq * 72 + cc] = f2bf(p);
      }
    // no barrier: same-wave write->read, compiler inserts lgkmcnt

    bf16x8 pf[2], vf[4][2];
#pragma unroll
    for (int kk = 0; kk < 2; ++kk)
      pf[kk] = *reinterpret_cast<const bf16x8*>(&Pb[l15 * 72 + kk * 32 + g * 8]);
#pragma unroll
    for (int nd = 0; nd < 4; ++nd)
#pragma unroll
      for (int kk = 0; kk < 2; ++kk)
        vf[nd][kk] = *reinterpret_cast<const bf16x8*>(
            Vh + (nd * 16 + l15) * T_DIM + kt * 64 + kk * 32 + g * 8);
#pragma unroll
    for (int nd = 0; nd < 4; ++nd)
#pragma unroll
      for (int kk = 0; kk < 2; ++kk)
        yac[nd] = __builtin_amdgcn_mfma_f32_16x16x32_bf16(pf[kk], vf[nd][kk], yac[nd], 0, 0, 0);

    // att store: this wave's 16 rows x 64 cols (f32), 128 chunks of 16B, 2 sweeps
#pragma unroll
    for (int it = 0; it < 2; ++it){
      const int chunk = (tid & 63) + it * 64;
      const int r = chunk >> 3, s = chunk & 7;
      union { int4 i4; ushort_t us[8]; } u;
      u.i4 = *reinterpret_cast<const int4*>(&Pb[r * 72 + s * 8]);
      f32x4 lo = { bf2f(u.us[0]), bf2f(u.us[1]), bf2f(u.us[2]), bf2f(u.us[3]) };
      f32x4 hi = { bf2f(u.us[4]), bf2f(u.us[5]), bf2f(u.us[6]), bf2f(u.us[7]) };
      float* dst = atth + (size_t)(q0 + w * 16 + r) * T_DIM + kt * 64 + s * 8;
      *reinterpret_cast<f32x4*>(dst)     = lo;
      *reinterpret_cast<f32x4*>(dst + 4) = hi;
    }
  }

  // zero-fill strictly-upper region (this wave's 16 rows; disjoint addresses)
  {
    const int zc0 = nkt * 64;
    const int cpr = (T_DIM - zc0) >> 2;
    if (cpr > 0){
      for (int r = 0; r < 16; ++r){
        f32x4* dst = reinterpret_cast<f32x4*>(
            atth + (size_t)(q0 + w * 16 + r) * T_DIM + zc0);
        for (int i = (tid & 63); i < cpr; i += 64)
          dst[i] = fz;
      }
    }
  }

  // y output: this wave's 16 rows
#pragma unroll
  for (int nd = 0; nd < 4; ++nd)
#pragma unroll
    for (int j = 0; j < 4; ++j){
      int t = q0 + w * 16 + g * 4 + j;
      int dcol = nd * 16 + l15;
      ya[t * C_DIM + h * D_DIM + dcol] = f2bf(yac[nd][j]);
    }
}

extern "C" void kernel_launch(void* const* d_in, const int* in_sizes, int n_in,
                              void* d_out, int out_size, void* d_ws, size_t ws_size,
                              hipStream_t stream)
{
  const float* x  = (const float*)d_in[0];
  const float* Wq = (const float*)d_in[1];
  const float* bq = (const float*)d_in[2];
  const float* Wk = (const float*)d_in[3];
  const float* bk = (const float*)d_in[4];
  const float* Wv = (const float*)d_in[5];
  const float* bv = (const float*)d_in[6];
  const float* Wp = (const float*)d_in[7];
  const float* bp = (const float*)d_in[8];
  float* out = (float*)d_out;            // f32: y [2048*1024], att [16*2048*2048]
  char* ws = (char*)d_ws;

  ushort_t* xb  = (ushort_t*)(ws);                   // 4 MB
  ushort_t* wtq = (ushort_t*)(ws + (4u  << 20));     // 2 MB each
  ushort_t* wtk = (ushort_t*)(ws + (6u  << 20));
  ushort_t* wtv = (ushort_t*)(ws + (8u  << 20));
  ushort_t* wtp = (ushort_t*)(ws + (10u << 20));
  ushort_t* Qb  = (ushort_t*)(ws + (12u << 20));     // 4 MB each
  ushort_t* Kb  = (ushort_t*)(ws + (16u << 20));
  ushort_t* Vt  = (ushort_t*)(ws + (20u << 20));
  ushort_t* ya  = (ushort_t*)(ws + (24u << 20));     // 4 MB

  hipLaunchKernelGGL(prep_kernel, dim3(3072), dim3(256), 0, stream,
                     x, xb, Wq, Wk, Wv, Wp, wtq, wtk, wtv, wtp);
  hipLaunchKernelGGL((gemm_kernel<0>), dim3(32, 24), dim3(256), 0, stream,
                     xb, wtq, wtk, wtv, bq, bk, bv, Qb, Kb, Vt, nullptr);
  hipLaunchKernelGGL(rope_kernel, dim3(8192), dim3(256), 0, stream, Qb, Kb);
  hipLaunchKernelGGL(attn_kernel, dim3(512), dim3(256), 0, stream,
                     Qb, Kb, Vt, out + 2097152, ya);
  hipLaunchKernelGGL((gemm_kernel<1>), dim3(32, 8), dim3(256), 0, stream,
                     ya, wtp, nullptr, nullptr, bp, nullptr, nullptr,
                     nullptr, nullptr, nullptr, out);
}

// Round 20
// 160.059 us; speedup vs baseline: 1.1780x; 1.1780x over previous
//
#include <hip/hip_runtime.h>

typedef unsigned short ushort_t;
typedef __bf16 bf16x8 __attribute__((ext_vector_type(8)));
typedef float f32x4 __attribute__((ext_vector_type(4)));

#define T_DIM 2048
#define C_DIM 1024
#define H_NUM 16
#define D_DIM 64

__device__ __forceinline__ ushort_t f2bf(float f){
  unsigned v = __float_as_uint(f);
  return (ushort_t)((v + 0x7fffu + ((v >> 16) & 1u)) >> 16);
}
__device__ __forceinline__ float bf2f(ushort_t u){
  return __uint_as_float(((unsigned)u) << 16);
}

typedef __attribute__((address_space(1))) const unsigned int* gas1_t;
typedef __attribute__((address_space(3))) unsigned int* las3_t;

__device__ __forceinline__ void gload_lds16(const void* g, void* l){
  __builtin_amdgcn_global_load_lds((gas1_t)g, (las3_t)l, 16, 0, 0);
}

// ---------------- prep: convert x (blocks >=1024) + transpose 4 weights ----------------
__global__ __launch_bounds__(256) void prep_kernel(
    const float* __restrict__ x, ushort_t* __restrict__ xb,
    const float* __restrict__ w0, const float* __restrict__ w1,
    const float* __restrict__ w2, const float* __restrict__ w3,
    ushort_t* __restrict__ t0, ushort_t* __restrict__ t1,
    ushort_t* __restrict__ t2, ushort_t* __restrict__ t3)
{
  __shared__ float tl[64][65];
  const int bid = blockIdx.x;
  const int tid = threadIdx.x;
  if (bid >= 1024){
    int i = ((bid - 1024) * 256 + tid) * 4;
    float4 v = *reinterpret_cast<const float4*>(x + i);
    ushort4 o;
    o.x = f2bf(v.x); o.y = f2bf(v.y); o.z = f2bf(v.z); o.w = f2bf(v.w);
    *reinterpret_cast<ushort4*>(xb + i) = o;
    return;
  }
  const int which = bid >> 8;
  const float* W = which==0 ? w0 : which==1 ? w1 : which==2 ? w2 : w3;
  ushort_t* WT   = which==0 ? t0 : which==1 ? t1 : which==2 ? t2 : t3;
  const int tile = bid & 255;
  const int k0 = (tile & 15) * 64;
  const int n0 = (tile >> 4) * 64;
#pragma unroll
  for (int i = 0; i < 16; ++i){
    int idx = tid + i * 256;
    int r = idx >> 6, c = idx & 63;
    tl[r][c] = W[(k0 + r) * C_DIM + n0 + c];
  }
  __syncthreads();
#pragma unroll
  for (int i = 0; i < 16; ++i){
    int idx = tid + i * 256;
    int r = idx >> 6, c = idx & 63;
    WT[(n0 + r) * C_DIM + k0 + c] = f2bf(tl[c][r]);
  }
}

// ---------------- GEMM: BM=64 x BN=128 ----------------
template<int MODE>
__global__ __launch_bounds__(256) void gemm_kernel(
    const ushort_t* __restrict__ A,
    const ushort_t* __restrict__ bt0, const ushort_t* __restrict__ bt1, const ushort_t* __restrict__ bt2,
    const float* __restrict__ bias0, const float* __restrict__ bias1, const float* __restrict__ bias2,
    ushort_t* __restrict__ o0, ushort_t* __restrict__ o1, ushort_t* __restrict__ o2,
    float* __restrict__ fo)
{
  __shared__ __align__(16) ushort_t Alds[64 * 32];
  __shared__ __align__(16) ushort_t Blds[128 * 32];
  const int tid = threadIdx.x;
  const int l15 = tid & 15, g = (tid & 63) >> 4;
  const int w = tid >> 6, wr = w >> 1, wc = w & 1;
  const int m0 = blockIdx.x * 64;
  int byy = blockIdx.y;
  int sel = 0;
  const ushort_t* BT; const float* bias; ushort_t* outp;
  if (MODE == 0){
    sel = byy >> 3; byy &= 7;
    BT   = sel==0 ? bt0 : (sel==1 ? bt1 : bt2);
    bias = sel==0 ? bias0 : (sel==1 ? bias1 : bias2);
    outp = sel==0 ? o0 : (sel==1 ? o1 : o2);
  } else { BT = bt0; bias = bias0; outp = o0; }
  const int n0 = byy * 128;

  const int c0 = tid, c1 = tid + 256;
  const ushort_t* Asrc  = A + (m0 + (c0 >> 2)) * C_DIM + (c0 & 3) * 8;
  const ushort_t* Bsrc0 = BT + (n0 + (c0 >> 2)) * C_DIM + (c0 & 3) * 8;
  const ushort_t* Bsrc1 = BT + (n0 + (c1 >> 2)) * C_DIM + (c1 & 3) * 8;

  f32x4 acc[2][4] = {};

  for (int kt = 0; kt < 32; ++kt){
    const int ko = kt * 32;
    gload_lds16(Asrc + ko, &Alds[c0 * 8]);
    gload_lds16(Bsrc0 + ko, &Blds[c0 * 8]);
    gload_lds16(Bsrc1 + ko, &Blds[c1 * 8]);
    __syncthreads();
    bf16x8 af[2], bfr[4];
#pragma unroll
    for (int i = 0; i < 2; ++i)
      af[i] = *reinterpret_cast<const bf16x8*>(&Alds[(wr * 32 + i * 16 + l15) * 32 + g * 8]);
#pragma unroll
    for (int j = 0; j < 4; ++j)
      bfr[j] = *reinterpret_cast<const bf16x8*>(&Blds[(wc * 64 + j * 16 + l15) * 32 + g * 8]);
#pragma unroll
    for (int i = 0; i < 2; ++i)
#pragma unroll
      for (int j = 0; j < 4; ++j)
        acc[i][j] = __builtin_amdgcn_mfma_f32_16x16x32_bf16(af[i], bfr[j], acc[i][j], 0, 0, 0);
    __syncthreads();
  }

  float bvv[4];
#pragma unroll
  for (int j = 0; j < 4; ++j) bvv[j] = bias[n0 + wc * 64 + j * 16 + l15];

  if (MODE == 1){
#pragma unroll
    for (int i = 0; i < 2; ++i)
#pragma unroll
      for (int j = 0; j < 4; ++j)
#pragma unroll
        for (int e = 0; e < 4; ++e){
          int t = m0 + wr * 32 + i * 16 + g * 4 + e;
          int c = n0 + wc * 64 + j * 16 + l15;
          fo[t * C_DIM + c] = acc[i][j][e] + bvv[j];
        }
    return;
  }

  if (sel == 2){
#pragma unroll
    for (int i = 0; i < 2; ++i){
#pragma unroll
      for (int j = 0; j < 4; ++j){
        int c = n0 + wc * 64 + j * 16 + l15;
        int hh = c >> 6, d = c & 63;
        int t0e = m0 + wr * 32 + i * 16 + g * 4;
        ushort4 o;
        o.x = f2bf(acc[i][j][0] + bvv[j]);
        o.y = f2bf(acc[i][j][1] + bvv[j]);
        o.z = f2bf(acc[i][j][2] + bvv[j]);
        o.w = f2bf(acc[i][j][3] + bvv[j]);
        *reinterpret_cast<ushort4*>(outp + (size_t)(hh * D_DIM + d) * T_DIM + t0e) = o;
      }
    }
  } else {
#pragma unroll
    for (int i = 0; i < 2; ++i){
#pragma unroll
      for (int j = 0; j < 4; ++j){
#pragma unroll
        for (int e = 0; e < 4; ++e){
          int t = m0 + wr * 32 + i * 16 + g * 4 + e;
          int c = n0 + wc * 64 + j * 16 + l15;
          int hh = c >> 6, d = c & 63;
          outp[((size_t)(hh * T_DIM) + t) * D_DIM + d] = f2bf(acc[i][j][e] + bvv[j]);
        }
      }
    }
  }
}

// ---------------- RoPE ----------------
__global__ void rope_kernel(ushort_t* __restrict__ Qb, ushort_t* __restrict__ Kb){
  int gid = blockIdx.x * 256 + threadIdx.x;
  int which = gid >> 20;
  int r = gid & ((1 << 20) - 1);
  int i = r & 31;
  int t = (r >> 5) & 2047;
  int hh = r >> 16;
  ushort_t* P = which ? Kb : Qb;
  unsigned* p = reinterpret_cast<unsigned*>(P + ((hh * T_DIM) + t) * D_DIM + 2 * i);
  unsigned pv = *p;
  float x0 = bf2f((ushort_t)(pv & 0xffffu));
  float x1 = bf2f((ushort_t)(pv >> 16));
  float ang = (float)t * __expf((float)i * -0.2878231366242558f);
  float sn, cs;
  __sincosf(ang, &sn, &cs);
  float y0 = x0 * cs - x1 * sn;
  float y1 = x1 * cs + x0 * sn;
  *p = (unsigned)f2bf(y0) | (((unsigned)f2bf(y1)) << 16);
}

// ---------------- attention: R18 + pass-1 K-prefetch pipeline + setprio in pass 2 ----------------
// Grid 512 x 256 thr; xcd=lin&7 -> heads {2x,2x+1}; SNAKE qi (per-CU pair sums to 33).
// Pass 1: sum-only softmax, 2-stage register K-prefetch (no barriers -> true pipelining).
// Pass 2: R18 quadrant structure (shared K/V loads), dbuf Plds, setprio around MFMA.
__global__ __launch_bounds__(256) void attn_kernel(
    const ushort_t* __restrict__ Qb, const ushort_t* __restrict__ Kb,
    const ushort_t* __restrict__ Vt, float* __restrict__ att, ushort_t* __restrict__ ya)
{
  __shared__ __align__(16) ushort_t Plds[2][64 * 72];
  __shared__ float l_sh[64];

  const int tid = threadIdx.x;
  const int l15 = tid & 15, g = (tid & 63) >> 4;
  const int w = tid >> 6, wr = w >> 1, wc = w & 1;
  const int lin = (int)blockIdx.x;
  const int h = 2 * (lin & 7) + ((lin >> 3) & 1);
  const int r_ = lin >> 4;
  const int qi = (r_ < 16) ? (31 - r_) : (r_ - 16);   // snake: CU pair sums const
  const int q0 = qi * 64;
  const int nkt = qi + 1;

  const ushort_t* Qh = Qb + h * T_DIM * D_DIM;
  const ushort_t* Kh = Kb + h * T_DIM * D_DIM;
  const ushort_t* Vh = Vt + h * D_DIM * T_DIM;
  float* atth = att + (size_t)h * T_DIM * T_DIM;

  const f32x4 fz = {0.f, 0.f, 0.f, 0.f};
  const float scale = 0.125f;

  // ---- pass 1 (swapped, sum-only, 2-stage K prefetch) ----
  {
    const int qloc = w * 16 + l15;
    const int qglob = q0 + qloc;
    bf16x8 qT[2];
#pragma unroll
    for (int ks = 0; ks < 2; ++ks)
      qT[ks] = *reinterpret_cast<const bf16x8*>(Qh + qglob * D_DIM + ks * 32 + g * 8);

    float la[4] = {0.f, 0.f, 0.f, 0.f};

    bf16x8 kA[4][2], kB[4][2];
    const ushort_t* Krow = Kh + l15 * D_DIM + g * 8;
#pragma unroll
    for (int mblk = 0; mblk < 4; ++mblk)
#pragma unroll
      for (int ks = 0; ks < 2; ++ks)
        kA[mblk][ks] = *reinterpret_cast<const bf16x8*>(Krow + (mblk * 16) * D_DIM + ks * 32);

    for (int kt = 0; kt < nkt; ++kt){
      const bool even = !(kt & 1);
      bf16x8 (&kc)[4][2] = even ? kA : kB;
      bf16x8 (&kn)[4][2] = even ? kB : kA;
      if (kt + 1 < nkt){
        const ushort_t* Kn = Krow + ((kt + 1) * 64) * D_DIM;
#pragma unroll
        for (int mblk = 0; mblk < 4; ++mblk)
#pragma unroll
          for (int ks = 0; ks < 2; ++ks)
            kn[mblk][ks] = *reinterpret_cast<const bf16x8*>(Kn + (mblk * 16) * D_DIM + ks * 32);
      }
      f32x4 sc[4];
      sc[0] = fz; sc[1] = fz; sc[2] = fz; sc[3] = fz;
#pragma unroll
      for (int mblk = 0; mblk < 4; ++mblk)
#pragma unroll
        for (int ks = 0; ks < 2; ++ks)
          sc[mblk] = __builtin_amdgcn_mfma_f32_16x16x32_bf16(kc[mblk][ks], qT[ks], sc[mblk], 0, 0, 0);

      if (kt == qi){
        const int kbase = kt * 64 + g * 4;
#pragma unroll
        for (int mblk = 0; mblk < 4; ++mblk)
#pragma unroll
          for (int j = 0; j < 4; ++j){
            float s = sc[mblk][j] * scale;
            if ((kbase + mblk * 16 + j) > qglob) s = -1e30f;
            la[mblk] += __expf(s);
          }
      } else {
#pragma unroll
        for (int mblk = 0; mblk < 4; ++mblk)
#pragma unroll
          for (int j = 0; j < 4; ++j)
            la[mblk] += __expf(sc[mblk][j] * scale);
      }
    }

    float s = (la[0] + la[1]) + (la[2] + la[3]);
    s += __shfl_xor(s, 16);
    s += __shfl_xor(s, 32);
    if (g == 0) l_sh[qloc] = s;
  }
  __syncthreads();

  float Li[2][4];
#pragma unroll
  for (int ms = 0; ms < 2; ++ms)
#pragma unroll
    for (int j = 0; j < 4; ++j){
      int row = wr * 32 + ms * 16 + g * 4 + j;
      Li[ms][j] = 1.0f / l_sh[row];
    }

  bf16x8 qf[2][2];
#pragma unroll
  for (int ms = 0; ms < 2; ++ms)
#pragma unroll
    for (int ks = 0; ks < 2; ++ks)
      qf[ms][ks] = *reinterpret_cast<const bf16x8*>(
          Qh + (q0 + wr * 32 + ms * 16 + l15) * D_DIM + ks * 32 + g * 8);

  // ---- pass 2: recompute S, write att (f32, plain), accumulate y ----
  f32x4 yac[2][2];
  yac[0][0] = fz; yac[0][1] = fz; yac[1][0] = fz; yac[1][1] = fz;

  int pb = 0;
  for (int kt = 0; kt < nkt; ++kt){
    ushort_t* Pb = &Plds[pb][0];
    bf16x8 kf[2][2];
#pragma unroll
    for (int ns = 0; ns < 2; ++ns)
#pragma unroll
      for (int ks = 0; ks < 2; ++ks)
        kf[ns][ks] = *reinterpret_cast<const bf16x8*>(
            Kh + (kt * 64 + wc * 32 + ns * 16 + l15) * D_DIM + ks * 32 + g * 8);

    f32x4 sac[2][2];
    sac[0][0] = fz; sac[0][1] = fz; sac[1][0] = fz; sac[1][1] = fz;
    __builtin_amdgcn_s_setprio(1);
#pragma unroll
    for (int ms = 0; ms < 2; ++ms)
#pragma unroll
      for (int ns = 0; ns < 2; ++ns)
#pragma unroll
        for (int ks = 0; ks < 2; ++ks)
          sac[ms][ns] = __builtin_amdgcn_mfma_f32_16x16x32_bf16(qf[ms][ks], kf[ns][ks], sac[ms][ns], 0, 0, 0);
    __builtin_amdgcn_s_setprio(0);

    const bool diag = (kt == qi);
#pragma unroll
    for (int ms = 0; ms < 2; ++ms)
#pragma unroll
      for (int ns = 0; ns < 2; ++ns)
#pragma unroll
        for (int j = 0; j < 4; ++j){
          float s = sac[ms][ns][j] * scale;
          int qq = wr * 32 + ms * 16 + g * 4 + j;
          int cc = wc * 32 + ns * 16 + l15;
          if (diag && cc > qq) s = -1e30f;
          float p = __expf(s) * Li[ms][j];
          Pb[qq * 72 + cc] = f2bf(p);
        }
    __syncthreads();

    bf16x8 pf[2][2], vf[2][2];
#pragma unroll
    for (int ms = 0; ms < 2; ++ms)
#pragma unroll
      for (int kk = 0; kk < 2; ++kk)
        pf[ms][kk] = *reinterpret_cast<const bf16x8*>(
            &Pb[(wr * 32 + ms * 16 + l15) * 72 + kk * 32 + g * 8]);
#pragma unroll
    for (int nd = 0; nd < 2; ++nd)
#pragma unroll
      for (int kk = 0; kk < 2; ++kk)
        vf[nd][kk] = *reinterpret_cast<const bf16x8*>(
            Vh + (wc * 32 + nd * 16 + l15) * T_DIM + kt * 64 + kk * 32 + g * 8);
    __builtin_amdgcn_s_setprio(1);
#pragma unroll
    for (int ms = 0; ms < 2; ++ms)
#pragma unroll
      for (int nd = 0; nd < 2; ++nd)
#pragma unroll
        for (int kk = 0; kk < 2; ++kk)
          yac[ms][nd] = __builtin_amdgcn_mfma_f32_16x16x32_bf16(pf[ms][kk], vf[nd][kk], yac[ms][nd], 0, 0, 0);
    __builtin_amdgcn_s_setprio(0);

#pragma unroll
    for (int half = 0; half < 2; ++half){
      const int c = tid + half * 256;
      const int r = c >> 3, s = c & 7;
      union { int4 i4; ushort_t us[8]; } u;
      u.i4 = *reinterpret_cast<const int4*>(&Pb[r * 72 + s * 8]);
      f32x4 lo = { bf2f(u.us[0]), bf2f(u.us[1]), bf2f(u.us[2]), bf2f(u.us[3]) };
      f32x4 hi = { bf2f(u.us[4]), bf2f(u.us[5]), bf2f(u.us[6]), bf2f(u.us[7]) };
      float* dst = atth + (size_t)(q0 + r) * T_DIM + kt * 64 + s * 8;
      *reinterpret_cast<f32x4*>(dst)     = lo;
      *reinterpret_cast<f32x4*>(dst + 4) = hi;
    }
    pb ^= 1;
  }

  // zero-fill strictly-upper region
  const int zc0 = nkt * 64;
  const int cpr = (T_DIM - zc0) >> 2;
  if (cpr > 0){
    const f32x4 z = {0.f, 0.f, 0.f, 0.f};
    for (int r = 0; r < 64; ++r){
      f32x4* dst = reinterpret_cast<f32x4*>(atth + (size_t)(q0 + r) * T_DIM + zc0);
      for (int i = tid; i < cpr; i += 256)
        dst[i] = z;
    }
  }

  // y output (T, H*D) bf16
#pragma unroll
  for (int ms = 0; ms < 2; ++ms)
#pragma unroll
    for (int nd = 0; nd < 2; ++nd)
#pragma unroll
      for (int j = 0; j < 4; ++j){
        int t = q0 + wr * 32 + ms * 16 + g * 4 + j;
        int dcol = wc * 32 + nd * 16 + l15;
        ya[t * C_DIM + h * D_DIM + dcol] = f2bf(yac[ms][nd][j]);
      }
}

extern "C" void kernel_launch(void* const* d_in, const int* in_sizes, int n_in,
                              void* d_out, int out_size, void* d_ws, size_t ws_size,
                              hipStream_t stream)
{
  const float* x  = (const float*)d_in[0];
  const float* Wq = (const float*)d_in[1];
  const float* bq = (const float*)d_in[2];
  const float* Wk = (const float*)d_in[3];
  const float* bk = (const float*)d_in[4];
  const float* Wv = (const float*)d_in[5];
  const float* bv = (const float*)d_in[6];
  const float* Wp = (const float*)d_in[7];
  const float* bp = (const float*)d_in[8];
  float* out = (float*)d_out;            // f32: y [2048*1024], att [16*2048*2048]
  char* ws = (char*)d_ws;

  ushort_t* xb  = (ushort_t*)(ws);                   // 4 MB
  ushort_t* wtq = (ushort_t*)(ws + (4u  << 20));     // 2 MB each
  ushort_t* wtk = (ushort_t*)(ws + (6u  << 20));
  ushort_t* wtv = (ushort_t*)(ws + (8u  << 20));
  ushort_t* wtp = (ushort_t*)(ws + (10u << 20));
  ushort_t* Qb  = (ushort_t*)(ws + (12u << 20));     // 4 MB each
  ushort_t* Kb  = (ushort_t*)(ws + (16u << 20));
  ushort_t* Vt  = (ushort_t*)(ws + (20u << 20));
  ushort_t* ya  = (ushort_t*)(ws + (24u << 20));     // 4 MB

  hipLaunchKernelGGL(prep_kernel, dim3(3072), dim3(256), 0, stream,
                     x, xb, Wq, Wk, Wv, Wp, wtq, wtk, wtv, wtp);
  hipLaunchKernelGGL((gemm_kernel<0>), dim3(32, 24), dim3(256), 0, stream,
                     xb, wtq, wtk, wtv, bq, bk, bv, Qb, Kb, Vt, nullptr);
  hipLaunchKernelGGL(rope_kernel, dim3(8192), dim3(256), 0, stream, Qb, Kb);
  hipLaunchKernelGGL(attn_kernel, dim3(512), dim3(256), 0, stream,
                     Qb, Kb, Vt, out + 2097152, ya);
  hipLaunchKernelGGL((gemm_kernel<1>), dim3(32, 8), dim3(256), 0, stream,
                     ya, wtp, nullptr, nullptr, bp, nullptr, nullptr,
                     nullptr, nullptr, nullptr, out);
}

// Round 21
// 155.773 us; speedup vs baseline: 1.2104x; 1.0275x over previous
//
#include <hip/hip_runtime.h>

typedef unsigned short ushort_t;
typedef __bf16 bf16x8 __attribute__((ext_vector_type(8)));
typedef float f32x4 __attribute__((ext_vector_type(4)));

#define T_DIM 2048
#define C_DIM 1024
#define H_NUM 16
#define D_DIM 64

__device__ __forceinline__ ushort_t f2bf(float f){
  unsigned v = __float_as_uint(f);
  return (ushort_t)((v + 0x7fffu + ((v >> 16) & 1u)) >> 16);
}
__device__ __forceinline__ float bf2f(ushort_t u){
  return __uint_as_float(((unsigned)u) << 16);
}

typedef __attribute__((address_space(1))) const unsigned int* gas1_t;
typedef __attribute__((address_space(3))) unsigned int* las3_t;

__device__ __forceinline__ void gload_lds16(const void* g, void* l){
  __builtin_amdgcn_global_load_lds((gas1_t)g, (las3_t)l, 16, 0, 0);
}

// ---------------- prep: convert x (blocks >=1024) + transpose 4 weights ----------------
__global__ __launch_bounds__(256) void prep_kernel(
    const float* __restrict__ x, ushort_t* __restrict__ xb,
    const float* __restrict__ w0, const float* __restrict__ w1,
    const float* __restrict__ w2, const float* __restrict__ w3,
    ushort_t* __restrict__ t0, ushort_t* __restrict__ t1,
    ushort_t* __restrict__ t2, ushort_t* __restrict__ t3)
{
  __shared__ float tl[64][65];
  const int bid = blockIdx.x;
  const int tid = threadIdx.x;
  if (bid >= 1024){
    int i = ((bid - 1024) * 256 + tid) * 4;
    float4 v = *reinterpret_cast<const float4*>(x + i);
    ushort4 o;
    o.x = f2bf(v.x); o.y = f2bf(v.y); o.z = f2bf(v.z); o.w = f2bf(v.w);
    *reinterpret_cast<ushort4*>(xb + i) = o;
    return;
  }
  const int which = bid >> 8;
  const float* W = which==0 ? w0 : which==1 ? w1 : which==2 ? w2 : w3;
  ushort_t* WT   = which==0 ? t0 : which==1 ? t1 : which==2 ? t2 : t3;
  const int tile = bid & 255;
  const int k0 = (tile & 15) * 64;
  const int n0 = (tile >> 4) * 64;
#pragma unroll
  for (int i = 0; i < 16; ++i){
    int idx = tid + i * 256;
    int r = idx >> 6, c = idx & 63;
    tl[r][c] = W[(k0 + r) * C_DIM + n0 + c];
  }
  __syncthreads();
#pragma unroll
  for (int i = 0; i < 16; ++i){
    int idx = tid + i * 256;
    int r = idx >> 6, c = idx & 63;
    WT[(n0 + r) * C_DIM + k0 + c] = f2bf(tl[c][r]);
  }
}

// ---------------- GEMM: BM=64 x BN=128 ----------------
template<int MODE>
__global__ __launch_bounds__(256) void gemm_kernel(
    const ushort_t* __restrict__ A,
    const ushort_t* __restrict__ bt0, const ushort_t* __restrict__ bt1, const ushort_t* __restrict__ bt2,
    const float* __restrict__ bias0, const float* __restrict__ bias1, const float* __restrict__ bias2,
    ushort_t* __restrict__ o0, ushort_t* __restrict__ o1, ushort_t* __restrict__ o2,
    float* __restrict__ fo)
{
  __shared__ __align__(16) ushort_t Alds[64 * 32];
  __shared__ __align__(16) ushort_t Blds[128 * 32];
  const int tid = threadIdx.x;
  const int l15 = tid & 15, g = (tid & 63) >> 4;
  const int w = tid >> 6, wr = w >> 1, wc = w & 1;
  const int m0 = blockIdx.x * 64;
  int byy = blockIdx.y;
  int sel = 0;
  const ushort_t* BT; const float* bias; ushort_t* outp;
  if (MODE == 0){
    sel = byy >> 3; byy &= 7;
    BT   = sel==0 ? bt0 : (sel==1 ? bt1 : bt2);
    bias = sel==0 ? bias0 : (sel==1 ? bias1 : bias2);
    outp = sel==0 ? o0 : (sel==1 ? o1 : o2);
  } else { BT = bt0; bias = bias0; outp = o0; }
  const int n0 = byy * 128;

  const int c0 = tid, c1 = tid + 256;
  const ushort_t* Asrc  = A + (m0 + (c0 >> 2)) * C_DIM + (c0 & 3) * 8;
  const ushort_t* Bsrc0 = BT + (n0 + (c0 >> 2)) * C_DIM + (c0 & 3) * 8;
  const ushort_t* Bsrc1 = BT + (n0 + (c1 >> 2)) * C_DIM + (c1 & 3) * 8;

  f32x4 acc[2][4] = {};

  for (int kt = 0; kt < 32; ++kt){
    const int ko = kt * 32;
    gload_lds16(Asrc + ko, &Alds[c0 * 8]);
    gload_lds16(Bsrc0 + ko, &Blds[c0 * 8]);
    gload_lds16(Bsrc1 + ko, &Blds[c1 * 8]);
    __syncthreads();
    bf16x8 af[2], bfr[4];
#pragma unroll
    for (int i = 0; i < 2; ++i)
      af[i] = *reinterpret_cast<const bf16x8*>(&Alds[(wr * 32 + i * 16 + l15) * 32 + g * 8]);
#pragma unroll
    for (int j = 0; j < 4; ++j)
      bfr[j] = *reinterpret_cast<const bf16x8*>(&Blds[(wc * 64 + j * 16 + l15) * 32 + g * 8]);
#pragma unroll
    for (int i = 0; i < 2; ++i)
#pragma unroll
      for (int j = 0; j < 4; ++j)
        acc[i][j] = __builtin_amdgcn_mfma_f32_16x16x32_bf16(af[i], bfr[j], acc[i][j], 0, 0, 0);
    __syncthreads();
  }

  float bvv[4];
#pragma unroll
  for (int j = 0; j < 4; ++j) bvv[j] = bias[n0 + wc * 64 + j * 16 + l15];

  if (MODE == 1){
#pragma unroll
    for (int i = 0; i < 2; ++i)
#pragma unroll
      for (int j = 0; j < 4; ++j)
#pragma unroll
        for (int e = 0; e < 4; ++e){
          int t = m0 + wr * 32 + i * 16 + g * 4 + e;
          int c = n0 + wc * 64 + j * 16 + l15;
          fo[t * C_DIM + c] = acc[i][j][e] + bvv[j];
        }
    return;
  }

  if (sel == 2){
#pragma unroll
    for (int i = 0; i < 2; ++i){
#pragma unroll
      for (int j = 0; j < 4; ++j){
        int c = n0 + wc * 64 + j * 16 + l15;
        int hh = c >> 6, d = c & 63;
        int t0e = m0 + wr * 32 + i * 16 + g * 4;
        ushort4 o;
        o.x = f2bf(acc[i][j][0] + bvv[j]);
        o.y = f2bf(acc[i][j][1] + bvv[j]);
        o.z = f2bf(acc[i][j][2] + bvv[j]);
        o.w = f2bf(acc[i][j][3] + bvv[j]);
        *reinterpret_cast<ushort4*>(outp + (size_t)(hh * D_DIM + d) * T_DIM + t0e) = o;
      }
    }
  } else {
#pragma unroll
    for (int i = 0; i < 2; ++i){
#pragma unroll
      for (int j = 0; j < 4; ++j){
#pragma unroll
        for (int e = 0; e < 4; ++e){
          int t = m0 + wr * 32 + i * 16 + g * 4 + e;
          int c = n0 + wc * 64 + j * 16 + l15;
          int hh = c >> 6, d = c & 63;
          outp[((size_t)(hh * T_DIM) + t) * D_DIM + d] = f2bf(acc[i][j][e] + bvv[j]);
        }
      }
    }
  }
}

// ---------------- RoPE ----------------
__global__ void rope_kernel(ushort_t* __restrict__ Qb, ushort_t* __restrict__ Kb){
  int gid = blockIdx.x * 256 + threadIdx.x;
  int which = gid >> 20;
  int r = gid & ((1 << 20) - 1);
  int i = r & 31;
  int t = (r >> 5) & 2047;
  int hh = r >> 16;
  ushort_t* P = which ? Kb : Qb;
  unsigned* p = reinterpret_cast<unsigned*>(P + ((hh * T_DIM) + t) * D_DIM + 2 * i);
  unsigned pv = *p;
  float x0 = bf2f((ushort_t)(pv & 0xffffu));
  float x1 = bf2f((ushort_t)(pv >> 16));
  float ang = (float)t * __expf((float)i * -0.2878231366242558f);
  float sn, cs;
  __sincosf(ang, &sn, &cs);
  float y0 = x0 * cs - x1 * sn;
  float y1 = x1 * cs + x0 * sn;
  *p = (unsigned)f2bf(y0) | (((unsigned)f2bf(y1)) << 16);
}

// ---------------- attention: snake + sum-only + pass-1 prefetch + TWO-TILE pass-2 phases ----
// Grid 512 x 256 thr; xcd=lin&7 -> heads {2x,2x+1}; SNAKE qi (per-CU pair sums to 33).
// Pass 2: 2 k-tiles per phase, 4 rotating LDS buffers, ONE barrier per 2 tiles.
// Buffer written at phase i is rewritten at phase i+2 with >=1 barrier between (safe).
__global__ __launch_bounds__(256) void attn_kernel(
    const ushort_t* __restrict__ Qb, const ushort_t* __restrict__ Kb,
    const ushort_t* __restrict__ Vt, float* __restrict__ att, ushort_t* __restrict__ ya)
{
  __shared__ __align__(16) ushort_t Plds[4][64 * 72];   // ~37 KB
  __shared__ float l_sh[64];

  const int tid = threadIdx.x;
  const int l15 = tid & 15, g = (tid & 63) >> 4;
  const int w = tid >> 6, wr = w >> 1, wc = w & 1;
  const int lin = (int)blockIdx.x;
  const int h = 2 * (lin & 7) + ((lin >> 3) & 1);
  const int r_ = lin >> 4;
  const int qi = (r_ < 16) ? (31 - r_) : (r_ - 16);   // snake
  const int q0 = qi * 64;
  const int nkt = qi + 1;

  const ushort_t* Qh = Qb + h * T_DIM * D_DIM;
  const ushort_t* Kh = Kb + h * T_DIM * D_DIM;
  const ushort_t* Vh = Vt + h * D_DIM * T_DIM;
  float* atth = att + (size_t)h * T_DIM * T_DIM;

  const f32x4 fz = {0.f, 0.f, 0.f, 0.f};
  const float scale = 0.125f;

  // ---- pass 1 (swapped, sum-only, 2-stage K prefetch) ----
  {
    const int qloc = w * 16 + l15;
    const int qglob = q0 + qloc;
    bf16x8 qT[2];
#pragma unroll
    for (int ks = 0; ks < 2; ++ks)
      qT[ks] = *reinterpret_cast<const bf16x8*>(Qh + qglob * D_DIM + ks * 32 + g * 8);

    float la[4] = {0.f, 0.f, 0.f, 0.f};

    bf16x8 kA[4][2], kB[4][2];
    const ushort_t* Krow = Kh + l15 * D_DIM + g * 8;
#pragma unroll
    for (int mblk = 0; mblk < 4; ++mblk)
#pragma unroll
      for (int ks = 0; ks < 2; ++ks)
        kA[mblk][ks] = *reinterpret_cast<const bf16x8*>(Krow + (mblk * 16) * D_DIM + ks * 32);

    for (int kt = 0; kt < nkt; ++kt){
      const bool even = !(kt & 1);
      bf16x8 (&kc)[4][2] = even ? kA : kB;
      bf16x8 (&kn)[4][2] = even ? kB : kA;
      if (kt + 1 < nkt){
        const ushort_t* Kn = Krow + ((kt + 1) * 64) * D_DIM;
#pragma unroll
        for (int mblk = 0; mblk < 4; ++mblk)
#pragma unroll
          for (int ks = 0; ks < 2; ++ks)
            kn[mblk][ks] = *reinterpret_cast<const bf16x8*>(Kn + (mblk * 16) * D_DIM + ks * 32);
      }
      f32x4 sc[4];
      sc[0] = fz; sc[1] = fz; sc[2] = fz; sc[3] = fz;
#pragma unroll
      for (int mblk = 0; mblk < 4; ++mblk)
#pragma unroll
        for (int ks = 0; ks < 2; ++ks)
          sc[mblk] = __builtin_amdgcn_mfma_f32_16x16x32_bf16(kc[mblk][ks], qT[ks], sc[mblk], 0, 0, 0);

      if (kt == qi){
        const int kbase = kt * 64 + g * 4;
#pragma unroll
        for (int mblk = 0; mblk < 4; ++mblk)
#pragma unroll
          for (int j = 0; j < 4; ++j){
            float s = sc[mblk][j] * scale;
            if ((kbase + mblk * 16 + j) > qglob) s = -1e30f;
            la[mblk] += __expf(s);
          }
      } else {
#pragma unroll
        for (int mblk = 0; mblk < 4; ++mblk)
#pragma unroll
          for (int j = 0; j < 4; ++j)
            la[mblk] += __expf(sc[mblk][j] * scale);
      }
    }

    float s = (la[0] + la[1]) + (la[2] + la[3]);
    s += __shfl_xor(s, 16);
    s += __shfl_xor(s, 32);
    if (g == 0) l_sh[qloc] = s;
  }
  __syncthreads();

  float Li[2][4];
#pragma unroll
  for (int ms = 0; ms < 2; ++ms)
#pragma unroll
    for (int j = 0; j < 4; ++j){
      int row = wr * 32 + ms * 16 + g * 4 + j;
      Li[ms][j] = 1.0f / l_sh[row];
    }

  bf16x8 qf[2][2];
#pragma unroll
  for (int ms = 0; ms < 2; ++ms)
#pragma unroll
    for (int ks = 0; ks < 2; ++ks)
      qf[ms][ks] = *reinterpret_cast<const bf16x8*>(
          Qh + (q0 + wr * 32 + ms * 16 + l15) * D_DIM + ks * 32 + g * 8);

  // ---- pass 2: two-tile phases ----
  f32x4 yac[2][2];
  yac[0][0] = fz; yac[0][1] = fz; yac[1][0] = fz; yac[1][1] = fz;

  auto qkt_phase = [&](int kt, ushort_t* Pb){
    bf16x8 kf[2][2];
#pragma unroll
    for (int ns = 0; ns < 2; ++ns)
#pragma unroll
      for (int ks = 0; ks < 2; ++ks)
        kf[ns][ks] = *reinterpret_cast<const bf16x8*>(
            Kh + (kt * 64 + wc * 32 + ns * 16 + l15) * D_DIM + ks * 32 + g * 8);
    f32x4 sac[2][2];
    sac[0][0] = fz; sac[0][1] = fz; sac[1][0] = fz; sac[1][1] = fz;
    __builtin_amdgcn_s_setprio(1);
#pragma unroll
    for (int ms = 0; ms < 2; ++ms)
#pragma unroll
      for (int ns = 0; ns < 2; ++ns)
#pragma unroll
        for (int ks = 0; ks < 2; ++ks)
          sac[ms][ns] = __builtin_amdgcn_mfma_f32_16x16x32_bf16(qf[ms][ks], kf[ns][ks], sac[ms][ns], 0, 0, 0);
    __builtin_amdgcn_s_setprio(0);
    const bool diag = (kt == qi);
#pragma unroll
    for (int ms = 0; ms < 2; ++ms)
#pragma unroll
      for (int ns = 0; ns < 2; ++ns)
#pragma unroll
        for (int j = 0; j < 4; ++j){
          float s = sac[ms][ns][j] * scale;
          int qq = wr * 32 + ms * 16 + g * 4 + j;
          int cc = wc * 32 + ns * 16 + l15;
          if (diag && cc > qq) s = -1e30f;
          float p = __expf(s) * Li[ms][j];
          Pb[qq * 72 + cc] = f2bf(p);
        }
  };

  auto pv_phase = [&](int kt, ushort_t* Pb){
    bf16x8 pf[2][2], vf[2][2];
#pragma unroll
    for (int ms = 0; ms < 2; ++ms)
#pragma unroll
      for (int kk = 0; kk < 2; ++kk)
        pf[ms][kk] = *reinterpret_cast<const bf16x8*>(
            &Pb[(wr * 32 + ms * 16 + l15) * 72 + kk * 32 + g * 8]);
#pragma unroll
    for (int nd = 0; nd < 2; ++nd)
#pragma unroll
      for (int kk = 0; kk < 2; ++kk)
        vf[nd][kk] = *reinterpret_cast<const bf16x8*>(
            Vh + (wc * 32 + nd * 16 + l15) * T_DIM + kt * 64 + kk * 32 + g * 8);
    __builtin_amdgcn_s_setprio(1);
#pragma unroll
    for (int ms = 0; ms < 2; ++ms)
#pragma unroll
      for (int nd = 0; nd < 2; ++nd)
#pragma unroll
        for (int kk = 0; kk < 2; ++kk)
          yac[ms][nd] = __builtin_amdgcn_mfma_f32_16x16x32_bf16(pf[ms][kk], vf[nd][kk], yac[ms][nd], 0, 0, 0);
    __builtin_amdgcn_s_setprio(0);
#pragma unroll
    for (int half = 0; half < 2; ++half){
      const int c = tid + half * 256;
      const int r = c >> 3, s = c & 7;
      union { int4 i4; ushort_t us[8]; } u;
      u.i4 = *reinterpret_cast<const int4*>(&Pb[r * 72 + s * 8]);
      f32x4 lo = { bf2f(u.us[0]), bf2f(u.us[1]), bf2f(u.us[2]), bf2f(u.us[3]) };
      f32x4 hi = { bf2f(u.us[4]), bf2f(u.us[5]), bf2f(u.us[6]), bf2f(u.us[7]) };
      float* dst = atth + (size_t)(q0 + r) * T_DIM + kt * 64 + s * 8;
      *reinterpret_cast<f32x4*>(dst)     = lo;
      *reinterpret_cast<f32x4*>(dst + 4) = hi;
    }
  };

  int phase = 0;
  int kt = 0;
  for (; kt + 1 < nkt; kt += 2){
    qkt_phase(kt,     &Plds[phase][0]);
    qkt_phase(kt + 1, &Plds[phase | 1][0]);
    __syncthreads();                       // ONE barrier per 2 tiles
    pv_phase(kt,      &Plds[phase][0]);
    pv_phase(kt + 1,  &Plds[phase | 1][0]);
    phase ^= 2;                            // rotate buffer pair; reuse after 2 barriers
  }
  if (kt < nkt){                           // odd tail (diag tile when nkt odd)
    qkt_phase(kt, &Plds[phase][0]);
    __syncthreads();
    pv_phase(kt, &Plds[phase][0]);
  }

  // zero-fill strictly-upper region
  const int zc0 = nkt * 64;
  const int cpr = (T_DIM - zc0) >> 2;
  if (cpr > 0){
    const f32x4 z = {0.f, 0.f, 0.f, 0.f};
    for (int r = 0; r < 64; ++r){
      f32x4* dst = reinterpret_cast<f32x4*>(atth + (size_t)(q0 + r) * T_DIM + zc0);
      for (int i = tid; i < cpr; i += 256)
        dst[i] = z;
    }
  }

  // y output (T, H*D) bf16
#pragma unroll
  for (int ms = 0; ms < 2; ++ms)
#pragma unroll
    for (int nd = 0; nd < 2; ++nd)
#pragma unroll
      for (int j = 0; j < 4; ++j){
        int t = q0 + wr * 32 + ms * 16 + g * 4 + j;
        int dcol = wc * 32 + nd * 16 + l15;
        ya[t * C_DIM + h * D_DIM + dcol] = f2bf(yac[ms][nd][j]);
      }
}

extern "C" void kernel_launch(void* const* d_in, const int* in_sizes, int n_in,
                              void* d_out, int out_size, void* d_ws, size_t ws_size,
                              hipStream_t stream)
{
  const float* x  = (const float*)d_in[0];
  const float* Wq = (const float*)d_in[1];
  const float* bq = (const float*)d_in[2];
  const float* Wk = (const float*)d_in[3];
  const float* bk = (const float*)d_in[4];
  const float* Wv = (const float*)d_in[5];
  const float* bv = (const float*)d_in[6];
  const float* Wp = (const float*)d_in[7];
  const float* bp = (const float*)d_in[8];
  float* out = (float*)d_out;            // f32: y [2048*1024], att [16*2048*2048]
  char* ws = (char*)d_ws;

  ushort_t* xb  = (ushort_t*)(ws);                   // 4 MB
  ushort_t* wtq = (ushort_t*)(ws + (4u  << 20));     // 2 MB each
  ushort_t* wtk = (ushort_t*)(ws + (6u  << 20));
  ushort_t* wtv = (ushort_t*)(ws + (8u  << 20));
  ushort_t* wtp = (ushort_t*)(ws + (10u << 20));
  ushort_t* Qb  = (ushort_t*)(ws + (12u << 20));     // 4 MB each
  ushort_t* Kb  = (ushort_t*)(ws + (16u << 20));
  ushort_t* Vt  = (ushort_t*)(ws + (20u << 20));
  ushort_t* ya  = (ushort_t*)(ws + (24u << 20));     // 4 MB

  hipLaunchKernelGGL(prep_kernel, dim3(3072), dim3(256), 0, stream,
                     x, xb, Wq, Wk, Wv, Wp, wtq, wtk, wtv, wtp);
  hipLaunchKernelGGL((gemm_kernel<0>), dim3(32, 24), dim3(256), 0, stream,
                     xb, wtq, wtk, wtv, bq, bk, bv, Qb, Kb, Vt, nullptr);
  hipLaunchKernelGGL(rope_kernel, dim3(8192), dim3(256), 0, stream, Qb, Kb);
  hipLaunchKernelGGL(attn_kernel, dim3(512), dim3(256), 0, stream,
                     Qb, Kb, Vt, out + 2097152, ya);
  hipLaunchKernelGGL((gemm_kernel<1>), dim3(32, 8), dim3(256), 0, stream,
                     ya, wtp, nullptr, nullptr, bp, nullptr, nullptr,
                     nullptr, nullptr, nullptr, out);
}

// Round 22
// 155.390 us; speedup vs baseline: 1.2134x; 1.0025x over previous
//
#include <hip/hip_runtime.h>

typedef unsigned short ushort_t;
typedef __bf16 bf16x8 __attribute__((ext_vector_type(8)));
typedef float f32x4 __attribute__((ext_vector_type(4)));

#define T_DIM 2048
#define C_DIM 1024
#define H_NUM 16
#define D_DIM 64

__device__ __forceinline__ ushort_t f2bf(float f){
  unsigned v = __float_as_uint(f);
  return (ushort_t)((v + 0x7fffu + ((v >> 16) & 1u)) >> 16);
}
__device__ __forceinline__ float bf2f(ushort_t u){
  return __uint_as_float(((unsigned)u) << 16);
}

typedef __attribute__((address_space(1))) const unsigned int* gas1_t;
typedef __attribute__((address_space(3))) unsigned int* las3_t;

__device__ __forceinline__ void gload_lds16(const void* g, void* l){
  __builtin_amdgcn_global_load_lds((gas1_t)g, (las3_t)l, 16, 0, 0);
}

// ---------------- prep: convert x (blocks >=1024) + transpose 4 weights ----------------
__global__ __launch_bounds__(256) void prep_kernel(
    const float* __restrict__ x, ushort_t* __restrict__ xb,
    const float* __restrict__ w0, const float* __restrict__ w1,
    const float* __restrict__ w2, const float* __restrict__ w3,
    ushort_t* __restrict__ t0, ushort_t* __restrict__ t1,
    ushort_t* __restrict__ t2, ushort_t* __restrict__ t3)
{
  __shared__ float tl[64][65];
  const int bid = blockIdx.x;
  const int tid = threadIdx.x;
  if (bid >= 1024){
    int i = ((bid - 1024) * 256 + tid) * 4;
    float4 v = *reinterpret_cast<const float4*>(x + i);
    ushort4 o;
    o.x = f2bf(v.x); o.y = f2bf(v.y); o.z = f2bf(v.z); o.w = f2bf(v.w);
    *reinterpret_cast<ushort4*>(xb + i) = o;
    return;
  }
  const int which = bid >> 8;
  const float* W = which==0 ? w0 : which==1 ? w1 : which==2 ? w2 : w3;
  ushort_t* WT   = which==0 ? t0 : which==1 ? t1 : which==2 ? t2 : t3;
  const int tile = bid & 255;
  const int k0 = (tile & 15) * 64;
  const int n0 = (tile >> 4) * 64;
#pragma unroll
  for (int i = 0; i < 16; ++i){
    int idx = tid + i * 256;
    int r = idx >> 6, c = idx & 63;
    tl[r][c] = W[(k0 + r) * C_DIM + n0 + c];
  }
  __syncthreads();
#pragma unroll
  for (int i = 0; i < 16; ++i){
    int idx = tid + i * 256;
    int r = idx >> 6, c = idx & 63;
    WT[(n0 + r) * C_DIM + k0 + c] = f2bf(tl[c][r]);
  }
}

// ---------------- GEMM: BM=64 x BN=128; MODE 0 epilogue stages via LDS for coalesced stores ----
template<int MODE>
__global__ __launch_bounds__(256) void gemm_kernel(
    const ushort_t* __restrict__ A,
    const ushort_t* __restrict__ bt0, const ushort_t* __restrict__ bt1, const ushort_t* __restrict__ bt2,
    const float* __restrict__ bias0, const float* __restrict__ bias1, const float* __restrict__ bias2,
    ushort_t* __restrict__ o0, ushort_t* __restrict__ o1, ushort_t* __restrict__ o2,
    float* __restrict__ fo)
{
  __shared__ __align__(16) ushort_t Alds[64 * 32];
  __shared__ __align__(16) ushort_t Blds[128 * 32];
  __shared__ __align__(16) ushort_t Est[2][64][72];   // epilogue staging (18.4 KB)
  const int tid = threadIdx.x;
  const int l15 = tid & 15, g = (tid & 63) >> 4;
  const int w = tid >> 6, wr = w >> 1, wc = w & 1;
  const int m0 = blockIdx.x * 64;
  int byy = blockIdx.y;
  int sel = 0;
  const ushort_t* BT; const float* bias; ushort_t* outp;
  if (MODE == 0){
    sel = byy >> 3; byy &= 7;
    BT   = sel==0 ? bt0 : (sel==1 ? bt1 : bt2);
    bias = sel==0 ? bias0 : (sel==1 ? bias1 : bias2);
    outp = sel==0 ? o0 : (sel==1 ? o1 : o2);
  } else { BT = bt0; bias = bias0; outp = o0; }
  const int n0 = byy * 128;

  const int c0 = tid, c1 = tid + 256;
  const ushort_t* Asrc  = A + (m0 + (c0 >> 2)) * C_DIM + (c0 & 3) * 8;
  const ushort_t* Bsrc0 = BT + (n0 + (c0 >> 2)) * C_DIM + (c0 & 3) * 8;
  const ushort_t* Bsrc1 = BT + (n0 + (c1 >> 2)) * C_DIM + (c1 & 3) * 8;

  f32x4 acc[2][4] = {};

  for (int kt = 0; kt < 32; ++kt){
    const int ko = kt * 32;
    gload_lds16(Asrc + ko, &Alds[c0 * 8]);
    gload_lds16(Bsrc0 + ko, &Blds[c0 * 8]);
    gload_lds16(Bsrc1 + ko, &Blds[c1 * 8]);
    __syncthreads();
    bf16x8 af[2], bfr[4];
#pragma unroll
    for (int i = 0; i < 2; ++i)
      af[i] = *reinterpret_cast<const bf16x8*>(&Alds[(wr * 32 + i * 16 + l15) * 32 + g * 8]);
#pragma unroll
    for (int j = 0; j < 4; ++j)
      bfr[j] = *reinterpret_cast<const bf16x8*>(&Blds[(wc * 64 + j * 16 + l15) * 32 + g * 8]);
#pragma unroll
    for (int i = 0; i < 2; ++i)
#pragma unroll
      for (int j = 0; j < 4; ++j)
        acc[i][j] = __builtin_amdgcn_mfma_f32_16x16x32_bf16(af[i], bfr[j], acc[i][j], 0, 0, 0);
    __syncthreads();
  }

  float bvv[4];
#pragma unroll
  for (int j = 0; j < 4; ++j) bvv[j] = bias[n0 + wc * 64 + j * 16 + l15];

  if (MODE == 1){
#pragma unroll
    for (int i = 0; i < 2; ++i)
#pragma unroll
      for (int j = 0; j < 4; ++j)
#pragma unroll
        for (int e = 0; e < 4; ++e){
          int t = m0 + wr * 32 + i * 16 + g * 4 + e;
          int c = n0 + wc * 64 + j * 16 + l15;
          fo[t * C_DIM + c] = acc[i][j][e] + bvv[j];
        }
    return;
  }

  // ---- MODE 0 epilogue: stage tile in LDS, then coalesced 16B store-out ----
  if (sel == 2){
    // V: stage transposed layout [d][t_local] (8B LDS writes along e)
#pragma unroll
    for (int i = 0; i < 2; ++i){
#pragma unroll
      for (int j = 0; j < 4; ++j){
        int d  = j * 16 + l15;
        int tl = wr * 32 + i * 16 + g * 4;
        ushort4 o;
        o.x = f2bf(acc[i][j][0] + bvv[j]);
        o.y = f2bf(acc[i][j][1] + bvv[j]);
        o.z = f2bf(acc[i][j][2] + bvv[j]);
        o.w = f2bf(acc[i][j][3] + bvv[j]);
        *reinterpret_cast<ushort4*>(&Est[wc][d][tl]) = o;
      }
    }
  } else {
    // Q/K: stage row-major [t_local][d]
#pragma unroll
    for (int i = 0; i < 2; ++i)
#pragma unroll
      for (int j = 0; j < 4; ++j)
#pragma unroll
        for (int e = 0; e < 4; ++e){
          int tl = wr * 32 + i * 16 + g * 4 + e;
          int d  = j * 16 + l15;
          Est[wc][tl][d] = f2bf(acc[i][j][e] + bvv[j]);
        }
  }
  __syncthreads();

  // coalesced store-out: 1024 chunks of 16B, 4 per thread
#pragma unroll
  for (int kk = 0; kk < 4; ++kk){
    const int cid = tid + kk * 256;
    const int buf = cid >> 9;              // which head half
    const int idx = cid & 511;
    const int r = idx >> 3, ccol = (idx & 7) * 8;
    int4 v = *reinterpret_cast<const int4*>(&Est[buf][r][ccol]);
    const int hh = (n0 >> 6) + buf;
    if (sel == 2){
      // V^T layout (H, D, T): row r = d, cols = t
      *reinterpret_cast<int4*>(outp + ((size_t)(hh * D_DIM + r)) * T_DIM + m0 + ccol) = v;
    } else {
      // (H, T, D): row r = t_local, cols = d
      *reinterpret_cast<int4*>(outp + ((size_t)(hh * T_DIM) + m0 + r) * D_DIM + ccol) = v;
    }
  }
}

// ---------------- RoPE ----------------
__global__ void rope_kernel(ushort_t* __restrict__ Qb, ushort_t* __restrict__ Kb){
  int gid = blockIdx.x * 256 + threadIdx.x;
  int which = gid >> 20;
  int r = gid & ((1 << 20) - 1);
  int i = r & 31;
  int t = (r >> 5) & 2047;
  int hh = r >> 16;
  ushort_t* P = which ? Kb : Qb;
  unsigned* p = reinterpret_cast<unsigned*>(P + ((hh * T_DIM) + t) * D_DIM + 2 * i);
  unsigned pv = *p;
  float x0 = bf2f((ushort_t)(pv & 0xffffu));
  float x1 = bf2f((ushort_t)(pv >> 16));
  float ang = (float)t * __expf((float)i * -0.2878231366242558f);
  float sn, cs;
  __sincosf(ang, &sn, &cs);
  float y0 = x0 * cs - x1 * sn;
  float y1 = x1 * cs + x0 * sn;
  *p = (unsigned)f2bf(y0) | (((unsigned)f2bf(y1)) << 16);
}

// ---------------- attention: snake + sum-only + pass-1 prefetch + two-tile pass-2 phases ----
// (identical to R21 best: 155.8 us)
__global__ __launch_bounds__(256) void attn_kernel(
    const ushort_t* __restrict__ Qb, const ushort_t* __restrict__ Kb,
    const ushort_t* __restrict__ Vt, float* __restrict__ att, ushort_t* __restrict__ ya)
{
  __shared__ __align__(16) ushort_t Plds[4][64 * 72];
  __shared__ float l_sh[64];

  const int tid = threadIdx.x;
  const int l15 = tid & 15, g = (tid & 63) >> 4;
  const int w = tid >> 6, wr = w >> 1, wc = w & 1;
  const int lin = (int)blockIdx.x;
  const int h = 2 * (lin & 7) + ((lin >> 3) & 1);
  const int r_ = lin >> 4;
  const int qi = (r_ < 16) ? (31 - r_) : (r_ - 16);   // snake
  const int q0 = qi * 64;
  const int nkt = qi + 1;

  const ushort_t* Qh = Qb + h * T_DIM * D_DIM;
  const ushort_t* Kh = Kb + h * T_DIM * D_DIM;
  const ushort_t* Vh = Vt + h * D_DIM * T_DIM;
  float* atth = att + (size_t)h * T_DIM * T_DIM;

  const f32x4 fz = {0.f, 0.f, 0.f, 0.f};
  const float scale = 0.125f;

  // ---- pass 1 (swapped, sum-only, 2-stage K prefetch) ----
  {
    const int qloc = w * 16 + l15;
    const int qglob = q0 + qloc;
    bf16x8 qT[2];
#pragma unroll
    for (int ks = 0; ks < 2; ++ks)
      qT[ks] = *reinterpret_cast<const bf16x8*>(Qh + qglob * D_DIM + ks * 32 + g * 8);

    float la[4] = {0.f, 0.f, 0.f, 0.f};

    bf16x8 kA[4][2], kB[4][2];
    const ushort_t* Krow = Kh + l15 * D_DIM + g * 8;
#pragma unroll
    for (int mblk = 0; mblk < 4; ++mblk)
#pragma unroll
      for (int ks = 0; ks < 2; ++ks)
        kA[mblk][ks] = *reinterpret_cast<const bf16x8*>(Krow + (mblk * 16) * D_DIM + ks * 32);

    for (int kt = 0; kt < nkt; ++kt){
      const bool even = !(kt & 1);
      bf16x8 (&kc)[4][2] = even ? kA : kB;
      bf16x8 (&kn)[4][2] = even ? kB : kA;
      if (kt + 1 < nkt){
        const ushort_t* Kn = Krow + ((kt + 1) * 64) * D_DIM;
#pragma unroll
        for (int mblk = 0; mblk < 4; ++mblk)
#pragma unroll
          for (int ks = 0; ks < 2; ++ks)
            kn[mblk][ks] = *reinterpret_cast<const bf16x8*>(Kn + (mblk * 16) * D_DIM + ks * 32);
      }
      f32x4 sc[4];
      sc[0] = fz; sc[1] = fz; sc[2] = fz; sc[3] = fz;
#pragma unroll
      for (int mblk = 0; mblk < 4; ++mblk)
#pragma unroll
        for (int ks = 0; ks < 2; ++ks)
          sc[mblk] = __builtin_amdgcn_mfma_f32_16x16x32_bf16(kc[mblk][ks], qT[ks], sc[mblk], 0, 0, 0);

      if (kt == qi){
        const int kbase = kt * 64 + g * 4;
#pragma unroll
        for (int mblk = 0; mblk < 4; ++mblk)
#pragma unroll
          for (int j = 0; j < 4; ++j){
            float s = sc[mblk][j] * scale;
            if ((kbase + mblk * 16 + j) > qglob) s = -1e30f;
            la[mblk] += __expf(s);
          }
      } else {
#pragma unroll
        for (int mblk = 0; mblk < 4; ++mblk)
#pragma unroll
          for (int j = 0; j < 4; ++j)
            la[mblk] += __expf(sc[mblk][j] * scale);
      }
    }

    float s = (la[0] + la[1]) + (la[2] + la[3]);
    s += __shfl_xor(s, 16);
    s += __shfl_xor(s, 32);
    if (g == 0) l_sh[qloc] = s;
  }
  __syncthreads();

  float Li[2][4];
#pragma unroll
  for (int ms = 0; ms < 2; ++ms)
#pragma unroll
    for (int j = 0; j < 4; ++j){
      int row = wr * 32 + ms * 16 + g * 4 + j;
      Li[ms][j] = 1.0f / l_sh[row];
    }

  bf16x8 qf[2][2];
#pragma unroll
  for (int ms = 0; ms < 2; ++ms)
#pragma unroll
    for (int ks = 0; ks < 2; ++ks)
      qf[ms][ks] = *reinterpret_cast<const bf16x8*>(
          Qh + (q0 + wr * 32 + ms * 16 + l15) * D_DIM + ks * 32 + g * 8);

  // ---- pass 2: two-tile phases ----
  f32x4 yac[2][2];
  yac[0][0] = fz; yac[0][1] = fz; yac[1][0] = fz; yac[1][1] = fz;

  auto qkt_phase = [&](int kt, ushort_t* Pb){
    bf16x8 kf[2][2];
#pragma unroll
    for (int ns = 0; ns < 2; ++ns)
#pragma unroll
      for (int ks = 0; ks < 2; ++ks)
        kf[ns][ks] = *reinterpret_cast<const bf16x8*>(
            Kh + (kt * 64 + wc * 32 + ns * 16 + l15) * D_DIM + ks * 32 + g * 8);
    f32x4 sac[2][2];
    sac[0][0] = fz; sac[0][1] = fz; sac[1][0] = fz; sac[1][1] = fz;
    __builtin_amdgcn_s_setprio(1);
#pragma unroll
    for (int ms = 0; ms < 2; ++ms)
#pragma unroll
      for (int ns = 0; ns < 2; ++ns)
#pragma unroll
        for (int ks = 0; ks < 2; ++ks)
          sac[ms][ns] = __builtin_amdgcn_mfma_f32_16x16x32_bf16(qf[ms][ks], kf[ns][ks], sac[ms][ns], 0, 0, 0);
    __builtin_amdgcn_s_setprio(0);
    const bool diag = (kt == qi);
#pragma unroll
    for (int ms = 0; ms < 2; ++ms)
#pragma unroll
      for (int ns = 0; ns < 2; ++ns)
#pragma unroll
        for (int j = 0; j < 4; ++j){
          float s = sac[ms][ns][j] * scale;
          int qq = wr * 32 + ms * 16 + g * 4 + j;
          int cc = wc * 32 + ns * 16 + l15;
          if (diag && cc > qq) s = -1e30f;
          float p = __expf(s) * Li[ms][j];
          Pb[qq * 72 + cc] = f2bf(p);
        }
  };

  auto pv_phase = [&](int kt, ushort_t* Pb){
    bf16x8 pf[2][2], vf[2][2];
#pragma unroll
    for (int ms = 0; ms < 2; ++ms)
#pragma unroll
      for (int kk = 0; kk < 2; ++kk)
        pf[ms][kk] = *reinterpret_cast<const bf16x8*>(
            &Pb[(wr * 32 + ms * 16 + l15) * 72 + kk * 32 + g * 8]);
#pragma unroll
    for (int nd = 0; nd < 2; ++nd)
#pragma unroll
      for (int kk = 0; kk < 2; ++kk)
        vf[nd][kk] = *reinterpret_cast<const bf16x8*>(
            Vh + (wc * 32 + nd * 16 + l15) * T_DIM + kt * 64 + kk * 32 + g * 8);
    __builtin_amdgcn_s_setprio(1);
#pragma unroll
    for (int ms = 0; ms < 2; ++ms)
#pragma unroll
      for (int nd = 0; nd < 2; ++nd)
#pragma unroll
        for (int kk = 0; kk < 2; ++kk)
          yac[ms][nd] = __builtin_amdgcn_mfma_f32_16x16x32_bf16(pf[ms][kk], vf[nd][kk], yac[ms][nd], 0, 0, 0);
    __builtin_amdgcn_s_setprio(0);
#pragma unroll
    for (int half = 0; half < 2; ++half){
      const int c = tid + half * 256;
      const int r = c >> 3, s = c & 7;
      union { int4 i4; ushort_t us[8]; } u;
      u.i4 = *reinterpret_cast<const int4*>(&Pb[r * 72 + s * 8]);
      f32x4 lo = { bf2f(u.us[0]), bf2f(u.us[1]), bf2f(u.us[2]), bf2f(u.us[3]) };
      f32x4 hi = { bf2f(u.us[4]), bf2f(u.us[5]), bf2f(u.us[6]), bf2f(u.us[7]) };
      float* dst = atth + (size_t)(q0 + r) * T_DIM + kt * 64 + s * 8;
      *reinterpret_cast<f32x4*>(dst)     = lo;
      *reinterpret_cast<f32x4*>(dst + 4) = hi;
    }
  };

  int phase = 0;
  int kt = 0;
  for (; kt + 1 < nkt; kt += 2){
    qkt_phase(kt,     &Plds[phase][0]);
    qkt_phase(kt + 1, &Plds[phase | 1][0]);
    __syncthreads();
    pv_phase(kt,      &Plds[phase][0]);
    pv_phase(kt + 1,  &Plds[phase | 1][0]);
    phase ^= 2;
  }
  if (kt < nkt){
    qkt_phase(kt, &Plds[phase][0]);
    __syncthreads();
    pv_phase(kt, &Plds[phase][0]);
  }

  // zero-fill strictly-upper region
  const int zc0 = nkt * 64;
  const int cpr = (T_DIM - zc0) >> 2;
  if (cpr > 0){
    const f32x4 z = {0.f, 0.f, 0.f, 0.f};
    for (int r = 0; r < 64; ++r){
      f32x4* dst = reinterpret_cast<f32x4*>(atth + (size_t)(q0 + r) * T_DIM + zc0);
      for (int i = tid; i < cpr; i += 256)
        dst[i] = z;
    }
  }

  // y output (T, H*D) bf16
#pragma unroll
  for (int ms = 0; ms < 2; ++ms)
#pragma unroll
    for (int nd = 0; nd < 2; ++nd)
#pragma unroll
      for (int j = 0; j < 4; ++j){
        int t = q0 + wr * 32 + ms * 16 + g * 4 + j;
        int dcol = wc * 32 + nd * 16 + l15;
        ya[t * C_DIM + h * D_DIM + dcol] = f2bf(yac[ms][nd][j]);
      }
}

extern "C" void kernel_launch(void* const* d_in, const int* in_sizes, int n_in,
                              void* d_out, int out_size, void* d_ws, size_t ws_size,
                              hipStream_t stream)
{
  const float* x  = (const float*)d_in[0];
  const float* Wq = (const float*)d_in[1];
  const float* bq = (const float*)d_in[2];
  const float* Wk = (const float*)d_in[3];
  const float* bk = (const float*)d_in[4];
  const float* Wv = (const float*)d_in[5];
  const float* bv = (const float*)d_in[6];
  const float* Wp = (const float*)d_in[7];
  const float* bp = (const float*)d_in[8];
  float* out = (float*)d_out;            // f32: y [2048*1024], att [16*2048*2048]
  char* ws = (char*)d_ws;

  ushort_t* xb  = (ushort_t*)(ws);                   // 4 MB
  ushort_t* wtq = (ushort_t*)(ws + (4u  << 20));     // 2 MB each
  ushort_t* wtk = (ushort_t*)(ws + (6u  << 20));
  ushort_t* wtv = (ushort_t*)(ws + (8u  << 20));
  ushort_t* wtp = (ushort_t*)(ws + (10u << 20));
  ushort_t* Qb  = (ushort_t*)(ws + (12u << 20));     // 4 MB each
  ushort_t* Kb  = (ushort_t*)(ws + (16u << 20));
  ushort_t* Vt  = (ushort_t*)(ws + (20u << 20));
  ushort_t* ya  = (ushort_t*)(ws + (24u << 20));     // 4 MB

  hipLaunchKernelGGL(prep_kernel, dim3(3072), dim3(256), 0, stream,
                     x, xb, Wq, Wk, Wv, Wp, wtq, wtk, wtv, wtp);
  hipLaunchKernelGGL((gemm_kernel<0>), dim3(32, 24), dim3(256), 0, stream,
                     xb, wtq, wtk, wtv, bq, bk, bv, Qb, Kb, Vt, nullptr);
  hipLaunchKernelGGL(rope_kernel, dim3(8192), dim3(256), 0, stream, Qb, Kb);
  hipLaunchKernelGGL(attn_kernel, dim3(512), dim3(256), 0, stream,
                     Qb, Kb, Vt, out + 2097152, ya);
  hipLaunchKernelGGL((gemm_kernel<1>), dim3(32, 8), dim3(256), 0, stream,
                     ya, wtp, nullptr, nullptr, bp, nullptr, nullptr,
                     nullptr, nullptr, nullptr, out);
}

// Round 23
// 151.476 us; speedup vs baseline: 1.2448x; 1.0258x over previous
//
#include <hip/hip_runtime.h>

typedef unsigned short ushort_t;
typedef __bf16 bf16x8 __attribute__((ext_vector_type(8)));
typedef float f32x4 __attribute__((ext_vector_type(4)));

#define T_DIM 2048
#define C_DIM 1024
#define H_NUM 16
#define D_DIM 64

__device__ __forceinline__ ushort_t f2bf(float f){
  unsigned v = __float_as_uint(f);
  return (ushort_t)((v + 0x7fffu + ((v >> 16) & 1u)) >> 16);
}
__device__ __forceinline__ float bf2f(ushort_t u){
  return __uint_as_float(((unsigned)u) << 16);
}

typedef __attribute__((address_space(1))) const unsigned int* gas1_t;
typedef __attribute__((address_space(3))) unsigned int* las3_t;

__device__ __forceinline__ void gload_lds16(const void* g, void* l){
  __builtin_amdgcn_global_load_lds((gas1_t)g, (las3_t)l, 16, 0, 0);
}

// ---------------- prep: convert x (blocks >=1024) + transpose 4 weights ----------------
__global__ __launch_bounds__(256) void prep_kernel(
    const float* __restrict__ x, ushort_t* __restrict__ xb,
    const float* __restrict__ w0, const float* __restrict__ w1,
    const float* __restrict__ w2, const float* __restrict__ w3,
    ushort_t* __restrict__ t0, ushort_t* __restrict__ t1,
    ushort_t* __restrict__ t2, ushort_t* __restrict__ t3)
{
  __shared__ float tl[64][65];
  const int bid = blockIdx.x;
  const int tid = threadIdx.x;
  if (bid >= 1024){
    int i = ((bid - 1024) * 256 + tid) * 4;
    float4 v = *reinterpret_cast<const float4*>(x + i);
    ushort4 o;
    o.x = f2bf(v.x); o.y = f2bf(v.y); o.z = f2bf(v.z); o.w = f2bf(v.w);
    *reinterpret_cast<ushort4*>(xb + i) = o;
    return;
  }
  const int which = bid >> 8;
  const float* W = which==0 ? w0 : which==1 ? w1 : which==2 ? w2 : w3;
  ushort_t* WT   = which==0 ? t0 : which==1 ? t1 : which==2 ? t2 : t3;
  const int tile = bid & 255;
  const int k0 = (tile & 15) * 64;
  const int n0 = (tile >> 4) * 64;
#pragma unroll
  for (int i = 0; i < 16; ++i){
    int idx = tid + i * 256;
    int r = idx >> 6, c = idx & 63;
    tl[r][c] = W[(k0 + r) * C_DIM + n0 + c];
  }
  __syncthreads();
#pragma unroll
  for (int i = 0; i < 16; ++i){
    int idx = tid + i * 256;
    int r = idx >> 6, c = idx & 63;
    WT[(n0 + r) * C_DIM + k0 + c] = f2bf(tl[c][r]);
  }
}

// ---------------- GEMM: BM=64 x BN=128; MODE 0 stages epilogue in LDS, RoPE fused ----
template<int MODE>
__global__ __launch_bounds__(256) void gemm_kernel(
    const ushort_t* __restrict__ A,
    const ushort_t* __restrict__ bt0, const ushort_t* __restrict__ bt1, const ushort_t* __restrict__ bt2,
    const float* __restrict__ bias0, const float* __restrict__ bias1, const float* __restrict__ bias2,
    ushort_t* __restrict__ o0, ushort_t* __restrict__ o1, ushort_t* __restrict__ o2,
    float* __restrict__ fo)
{
  __shared__ __align__(16) ushort_t Alds[64 * 32];
  __shared__ __align__(16) ushort_t Blds[128 * 32];
  __shared__ __align__(16) ushort_t Est[2][64][72];
  const int tid = threadIdx.x;
  const int l15 = tid & 15, g = (tid & 63) >> 4;
  const int w = tid >> 6, wr = w >> 1, wc = w & 1;
  const int m0 = blockIdx.x * 64;
  int byy = blockIdx.y;
  int sel = 0;
  const ushort_t* BT; const float* bias; ushort_t* outp;
  if (MODE == 0){
    sel = byy >> 3; byy &= 7;
    BT   = sel==0 ? bt0 : (sel==1 ? bt1 : bt2);
    bias = sel==0 ? bias0 : (sel==1 ? bias1 : bias2);
    outp = sel==0 ? o0 : (sel==1 ? o1 : o2);
  } else { BT = bt0; bias = bias0; outp = o0; }
  const int n0 = byy * 128;

  const int c0 = tid, c1 = tid + 256;
  const ushort_t* Asrc  = A + (m0 + (c0 >> 2)) * C_DIM + (c0 & 3) * 8;
  const ushort_t* Bsrc0 = BT + (n0 + (c0 >> 2)) * C_DIM + (c0 & 3) * 8;
  const ushort_t* Bsrc1 = BT + (n0 + (c1 >> 2)) * C_DIM + (c1 & 3) * 8;

  f32x4 acc[2][4] = {};

  for (int kt = 0; kt < 32; ++kt){
    const int ko = kt * 32;
    gload_lds16(Asrc + ko, &Alds[c0 * 8]);
    gload_lds16(Bsrc0 + ko, &Blds[c0 * 8]);
    gload_lds16(Bsrc1 + ko, &Blds[c1 * 8]);
    __syncthreads();
    bf16x8 af[2], bfr[4];
#pragma unroll
    for (int i = 0; i < 2; ++i)
      af[i] = *reinterpret_cast<const bf16x8*>(&Alds[(wr * 32 + i * 16 + l15) * 32 + g * 8]);
#pragma unroll
    for (int j = 0; j < 4; ++j)
      bfr[j] = *reinterpret_cast<const bf16x8*>(&Blds[(wc * 64 + j * 16 + l15) * 32 + g * 8]);
#pragma unroll
    for (int i = 0; i < 2; ++i)
#pragma unroll
      for (int j = 0; j < 4; ++j)
        acc[i][j] = __builtin_amdgcn_mfma_f32_16x16x32_bf16(af[i], bfr[j], acc[i][j], 0, 0, 0);
    __syncthreads();
  }

  float bvv[4];
#pragma unroll
  for (int j = 0; j < 4; ++j) bvv[j] = bias[n0 + wc * 64 + j * 16 + l15];

  if (MODE == 1){
#pragma unroll
    for (int i = 0; i < 2; ++i)
#pragma unroll
      for (int j = 0; j < 4; ++j)
#pragma unroll
        for (int e = 0; e < 4; ++e){
          int t = m0 + wr * 32 + i * 16 + g * 4 + e;
          int c = n0 + wc * 64 + j * 16 + l15;
          fo[t * C_DIM + c] = acc[i][j][e] + bvv[j];
        }
    return;
  }

  // ---- MODE 0 epilogue: stage tile in LDS ----
  if (sel == 2){
#pragma unroll
    for (int i = 0; i < 2; ++i){
#pragma unroll
      for (int j = 0; j < 4; ++j){
        int d  = j * 16 + l15;
        int tl = wr * 32 + i * 16 + g * 4;
        ushort4 o;
        o.x = f2bf(acc[i][j][0] + bvv[j]);
        o.y = f2bf(acc[i][j][1] + bvv[j]);
        o.z = f2bf(acc[i][j][2] + bvv[j]);
        o.w = f2bf(acc[i][j][3] + bvv[j]);
        *reinterpret_cast<ushort4*>(&Est[wc][d][tl]) = o;
      }
    }
  } else {
#pragma unroll
    for (int i = 0; i < 2; ++i)
#pragma unroll
      for (int j = 0; j < 4; ++j)
#pragma unroll
        for (int e = 0; e < 4; ++e){
          int tl = wr * 32 + i * 16 + g * 4 + e;
          int d  = j * 16 + l15;
          Est[wc][tl][d] = f2bf(acc[i][j][e] + bvv[j]);
        }
  }
  __syncthreads();

  // coalesced store-out: 1024 chunks of 16B, 4/thread; RoPE fused for Q/K (pairs intra-chunk)
#pragma unroll
  for (int kk = 0; kk < 4; ++kk){
    const int cid = tid + kk * 256;
    const int buf = cid >> 9;
    const int idx = cid & 511;
    const int r = idx >> 3, ccol = (idx & 7) * 8;
    const int hh = (n0 >> 6) + buf;
    if (sel == 2){
      int4 v = *reinterpret_cast<const int4*>(&Est[buf][r][ccol]);
      *reinterpret_cast<int4*>(outp + ((size_t)(hh * D_DIM + r)) * T_DIM + m0 + ccol) = v;
    } else {
      // RoPE: rotate interleaved pairs within the 8-element chunk
      union { int4 i4; ushort_t us[8]; } u;
      u.i4 = *reinterpret_cast<const int4*>(&Est[buf][r][ccol]);
      const float tf = (float)(m0 + r);
#pragma unroll
      for (int p = 0; p < 4; ++p){
        const int ii = (ccol >> 1) + p;
        float x0 = bf2f(u.us[2 * p]);
        float x1 = bf2f(u.us[2 * p + 1]);
        float ang = tf * __expf((float)ii * -0.2878231366242558f); // -2 ln(1e4)/64
        float sn, cs;
        __sincosf(ang, &sn, &cs);
        u.us[2 * p]     = f2bf(x0 * cs - x1 * sn);
        u.us[2 * p + 1] = f2bf(x1 * cs + x0 * sn);
      }
      *reinterpret_cast<int4*>(outp + ((size_t)(hh * T_DIM) + m0 + r) * D_DIM + ccol) = u.i4;
    }
  }
}

// ---------------- attention: snake + sum-only + pass-1 prefetch + two-tile pass-2 phases ----
__global__ __launch_bounds__(256) void attn_kernel(
    const ushort_t* __restrict__ Qb, const ushort_t* __restrict__ Kb,
    const ushort_t* __restrict__ Vt, float* __restrict__ att, ushort_t* __restrict__ ya)
{
  __shared__ __align__(16) ushort_t Plds[4][64 * 72];
  __shared__ float l_sh[64];

  const int tid = threadIdx.x;
  const int l15 = tid & 15, g = (tid & 63) >> 4;
  const int w = tid >> 6, wr = w >> 1, wc = w & 1;
  const int lin = (int)blockIdx.x;
  const int h = 2 * (lin & 7) + ((lin >> 3) & 1);
  const int r_ = lin >> 4;
  const int qi = (r_ < 16) ? (31 - r_) : (r_ - 16);   // snake
  const int q0 = qi * 64;
  const int nkt = qi + 1;

  const ushort_t* Qh = Qb + h * T_DIM * D_DIM;
  const ushort_t* Kh = Kb + h * T_DIM * D_DIM;
  const ushort_t* Vh = Vt + h * D_DIM * T_DIM;
  float* atth = att + (size_t)h * T_DIM * T_DIM;

  const f32x4 fz = {0.f, 0.f, 0.f, 0.f};
  const float scale = 0.125f;

  // ---- pass 1 (swapped, sum-only, 2-stage K prefetch) ----
  {
    const int qloc = w * 16 + l15;
    const int qglob = q0 + qloc;
    bf16x8 qT[2];
#pragma unroll
    for (int ks = 0; ks < 2; ++ks)
      qT[ks] = *reinterpret_cast<const bf16x8*>(Qh + qglob * D_DIM + ks * 32 + g * 8);

    float la[4] = {0.f, 0.f, 0.f, 0.f};

    bf16x8 kA[4][2], kB[4][2];
    const ushort_t* Krow = Kh + l15 * D_DIM + g * 8;
#pragma unroll
    for (int mblk = 0; mblk < 4; ++mblk)
#pragma unroll
      for (int ks = 0; ks < 2; ++ks)
        kA[mblk][ks] = *reinterpret_cast<const bf16x8*>(Krow + (mblk * 16) * D_DIM + ks * 32);

    for (int kt = 0; kt < nkt; ++kt){
      const bool even = !(kt & 1);
      bf16x8 (&kc)[4][2] = even ? kA : kB;
      bf16x8 (&kn)[4][2] = even ? kB : kA;
      if (kt + 1 < nkt){
        const ushort_t* Kn = Krow + ((kt + 1) * 64) * D_DIM;
#pragma unroll
        for (int mblk = 0; mblk < 4; ++mblk)
#pragma unroll
          for (int ks = 0; ks < 2; ++ks)
            kn[mblk][ks] = *reinterpret_cast<const bf16x8*>(Kn + (mblk * 16) * D_DIM + ks * 32);
      }
      f32x4 sc[4];
      sc[0] = fz; sc[1] = fz; sc[2] = fz; sc[3] = fz;
#pragma unroll
      for (int mblk = 0; mblk < 4; ++mblk)
#pragma unroll
        for (int ks = 0; ks < 2; ++ks)
          sc[mblk] = __builtin_amdgcn_mfma_f32_16x16x32_bf16(kc[mblk][ks], qT[ks], sc[mblk], 0, 0, 0);

      if (kt == qi){
        const int kbase = kt * 64 + g * 4;
#pragma unroll
        for (int mblk = 0; mblk < 4; ++mblk)
#pragma unroll
          for (int j = 0; j < 4; ++j){
            float s = sc[mblk][j] * scale;
            if ((kbase + mblk * 16 + j) > qglob) s = -1e30f;
            la[mblk] += __expf(s);
          }
      } else {
#pragma unroll
        for (int mblk = 0; mblk < 4; ++mblk)
#pragma unroll
          for (int j = 0; j < 4; ++j)
            la[mblk] += __expf(sc[mblk][j] * scale);
      }
    }

    float s = (la[0] + la[1]) + (la[2] + la[3]);
    s += __shfl_xor(s, 16);
    s += __shfl_xor(s, 32);
    if (g == 0) l_sh[qloc] = s;
  }
  __syncthreads();

  float Li[2][4];
#pragma unroll
  for (int ms = 0; ms < 2; ++ms)
#pragma unroll
    for (int j = 0; j < 4; ++j){
      int row = wr * 32 + ms * 16 + g * 4 + j;
      Li[ms][j] = 1.0f / l_sh[row];
    }

  bf16x8 qf[2][2];
#pragma unroll
  for (int ms = 0; ms < 2; ++ms)
#pragma unroll
    for (int ks = 0; ks < 2; ++ks)
      qf[ms][ks] = *reinterpret_cast<const bf16x8*>(
          Qh + (q0 + wr * 32 + ms * 16 + l15) * D_DIM + ks * 32 + g * 8);

  // ---- pass 2: two-tile phases ----
  f32x4 yac[2][2];
  yac[0][0] = fz; yac[0][1] = fz; yac[1][0] = fz; yac[1][1] = fz;

  auto qkt_phase = [&](int kt, ushort_t* Pb){
    bf16x8 kf[2][2];
#pragma unroll
    for (int ns = 0; ns < 2; ++ns)
#pragma unroll
      for (int ks = 0; ks < 2; ++ks)
        kf[ns][ks] = *reinterpret_cast<const bf16x8*>(
            Kh + (kt * 64 + wc * 32 + ns * 16 + l15) * D_DIM + ks * 32 + g * 8);
    f32x4 sac[2][2];
    sac[0][0] = fz; sac[0][1] = fz; sac[1][0] = fz; sac[1][1] = fz;
    __builtin_amdgcn_s_setprio(1);
#pragma unroll
    for (int ms = 0; ms < 2; ++ms)
#pragma unroll
      for (int ns = 0; ns < 2; ++ns)
#pragma unroll
        for (int ks = 0; ks < 2; ++ks)
          sac[ms][ns] = __builtin_amdgcn_mfma_f32_16x16x32_bf16(qf[ms][ks], kf[ns][ks], sac[ms][ns], 0, 0, 0);
    __builtin_amdgcn_s_setprio(0);
    const bool diag = (kt == qi);
#pragma unroll
    for (int ms = 0; ms < 2; ++ms)
#pragma unroll
      for (int ns = 0; ns < 2; ++ns)
#pragma unroll
        for (int j = 0; j < 4; ++j){
          float s = sac[ms][ns][j] * scale;
          int qq = wr * 32 + ms * 16 + g * 4 + j;
          int cc = wc * 32 + ns * 16 + l15;
          if (diag && cc > qq) s = -1e30f;
          float p = __expf(s) * Li[ms][j];
          Pb[qq * 72 + cc] = f2bf(p);
        }
  };

  auto pv_phase = [&](int kt, ushort_t* Pb){
    bf16x8 pf[2][2], vf[2][2];
#pragma unroll
    for (int ms = 0; ms < 2; ++ms)
#pragma unroll
      for (int kk = 0; kk < 2; ++kk)
        pf[ms][kk] = *reinterpret_cast<const bf16x8*>(
            &Pb[(wr * 32 + ms * 16 + l15) * 72 + kk * 32 + g * 8]);
#pragma unroll
    for (int nd = 0; nd < 2; ++nd)
#pragma unroll
      for (int kk = 0; kk < 2; ++kk)
        vf[nd][kk] = *reinterpret_cast<const bf16x8*>(
            Vh + (wc * 32 + nd * 16 + l15) * T_DIM + kt * 64 + kk * 32 + g * 8);
    __builtin_amdgcn_s_setprio(1);
#pragma unroll
    for (int ms = 0; ms < 2; ++ms)
#pragma unroll
      for (int nd = 0; nd < 2; ++nd)
#pragma unroll
        for (int kk = 0; kk < 2; ++kk)
          yac[ms][nd] = __builtin_amdgcn_mfma_f32_16x16x32_bf16(pf[ms][kk], vf[nd][kk], yac[ms][nd], 0, 0, 0);
    __builtin_amdgcn_s_setprio(0);
#pragma unroll
    for (int half = 0; half < 2; ++half){
      const int c = tid + half * 256;
      const int r = c >> 3, s = c & 7;
      union { int4 i4; ushort_t us[8]; } u;
      u.i4 = *reinterpret_cast<const int4*>(&Pb[r * 72 + s * 8]);
      f32x4 lo = { bf2f(u.us[0]), bf2f(u.us[1]), bf2f(u.us[2]), bf2f(u.us[3]) };
      f32x4 hi = { bf2f(u.us[4]), bf2f(u.us[5]), bf2f(u.us[6]), bf2f(u.us[7]) };
      float* dst = atth + (size_t)(q0 + r) * T_DIM + kt * 64 + s * 8;
      *reinterpret_cast<f32x4*>(dst)     = lo;
      *reinterpret_cast<f32x4*>(dst + 4) = hi;
    }
  };

  int phase = 0;
  int kt = 0;
  for (; kt + 1 < nkt; kt += 2){
    qkt_phase(kt,     &Plds[phase][0]);
    qkt_phase(kt + 1, &Plds[phase | 1][0]);
    __syncthreads();
    pv_phase(kt,      &Plds[phase][0]);
    pv_phase(kt + 1,  &Plds[phase | 1][0]);
    phase ^= 2;
  }
  if (kt < nkt){
    qkt_phase(kt, &Plds[phase][0]);
    __syncthreads();
    pv_phase(kt, &Plds[phase][0]);
  }

  // zero-fill strictly-upper region
  const int zc0 = nkt * 64;
  const int cpr = (T_DIM - zc0) >> 2;
  if (cpr > 0){
    const f32x4 z = {0.f, 0.f, 0.f, 0.f};
    for (int r = 0; r < 64; ++r){
      f32x4* dst = reinterpret_cast<f32x4*>(atth + (size_t)(q0 + r) * T_DIM + zc0);
      for (int i = tid; i < cpr; i += 256)
        dst[i] = z;
    }
  }

  // y output (T, H*D) bf16
#pragma unroll
  for (int ms = 0; ms < 2; ++ms)
#pragma unroll
    for (int nd = 0; nd < 2; ++nd)
#pragma unroll
      for (int j = 0; j < 4; ++j){
        int t = q0 + wr * 32 + ms * 16 + g * 4 + j;
        int dcol = wc * 32 + nd * 16 + l15;
        ya[t * C_DIM + h * D_DIM + dcol] = f2bf(yac[ms][nd][j]);
      }
}

extern "C" void kernel_launch(void* const* d_in, const int* in_sizes, int n_in,
                              void* d_out, int out_size, void* d_ws, size_t ws_size,
                              hipStream_t stream)
{
  const float* x  = (const float*)d_in[0];
  const float* Wq = (const float*)d_in[1];
  const float* bq = (const float*)d_in[2];
  const float* Wk = (const float*)d_in[3];
  const float* bk = (const float*)d_in[4];
  const float* Wv = (const float*)d_in[5];
  const float* bv = (const float*)d_in[6];
  const float* Wp = (const float*)d_in[7];
  const float* bp = (const float*)d_in[8];
  float* out = (float*)d_out;            // f32: y [2048*1024], att [16*2048*2048]
  char* ws = (char*)d_ws;

  ushort_t* xb  = (ushort_t*)(ws);                   // 4 MB
  ushort_t* wtq = (ushort_t*)(ws + (4u  << 20));     // 2 MB each
  ushort_t* wtk = (ushort_t*)(ws + (6u  << 20));
  ushort_t* wtv = (ushort_t*)(ws + (8u  << 20));
  ushort_t* wtp = (ushort_t*)(ws + (10u << 20));
  ushort_t* Qb  = (ushort_t*)(ws + (12u << 20));     // 4 MB each
  ushort_t* Kb  = (ushort_t*)(ws + (16u << 20));
  ushort_t* Vt  = (ushort_t*)(ws + (20u << 20));
  ushort_t* ya  = (ushort_t*)(ws + (24u << 20));     // 4 MB

  hipLaunchKernelGGL(prep_kernel, dim3(3072), dim3(256), 0, stream,
                     x, xb, Wq, Wk, Wv, Wp, wtq, wtk, wtv, wtp);
  hipLaunchKernelGGL((gemm_kernel<0>), dim3(32, 24), dim3(256), 0, stream,
                     xb, wtq, wtk, wtv, bq, bk, bv, Qb, Kb, Vt, nullptr);
  hipLaunchKernelGGL(attn_kernel, dim3(512), dim3(256), 0, stream,
                     Qb, Kb, Vt, out + 2097152, ya);
  hipLaunchKernelGGL((gemm_kernel<1>), dim3(32, 8), dim3(256), 0, stream,
                     ya, wtp, nullptr, nullptr, bp, nullptr, nullptr,
                     nullptr, nullptr, nullptr, out);
}